// Round 13
// baseline (1311.542 us; speedup 1.0000x reference)
//
#include <hip/hip_runtime.h>
#include <math.h>

// Problem constants (B,T,N,D) = (2,64,512,256)
#define B_ 2
#define T_ 64
#define N_ 512
#define D_ 256
#define M_ (B_*T_*N_)            // 65536 rows for the GEMMs
#define PLANE ((size_t)M_*D_)    // 16777216 elements per output plane

typedef unsigned short u16;
typedef __attribute__((ext_vector_type(8))) short bf16x8;
typedef __attribute__((ext_vector_type(4))) float f32x4;

__device__ __forceinline__ u16 f2bf(float f) {
  union { float f; unsigned u; } cv; cv.f = f;
  unsigned u = cv.u;
  return (u16)((u + 0x7FFFu + ((u >> 16) & 1u)) >> 16);   // RNE
}
__device__ __forceinline__ float bf2f(u16 h) {
  union { unsigned u; float f; } cv; cv.u = ((unsigned)h) << 16;
  return cv.f;
}

// 64-lane sum via DPP (VALU-only). Result wave-uniform via readlane 63.
__device__ __forceinline__ float wredsum(float x) {
  x += __uint_as_float(__builtin_amdgcn_update_dpp(0u, __float_as_uint(x), 0x111, 0xf, 0xf, true));
  x += __uint_as_float(__builtin_amdgcn_update_dpp(0u, __float_as_uint(x), 0x112, 0xf, 0xf, true));
  x += __uint_as_float(__builtin_amdgcn_update_dpp(0u, __float_as_uint(x), 0x114, 0xf, 0xf, true));
  x += __uint_as_float(__builtin_amdgcn_update_dpp(0u, __float_as_uint(x), 0x118, 0xf, 0xf, true));
  x += __uint_as_float(__builtin_amdgcn_update_dpp(0u, __float_as_uint(x), 0x142, 0xa, 0xf, true));
  x += __uint_as_float(__builtin_amdgcn_update_dpp(0u, __float_as_uint(x), 0x143, 0xc, 0xf, true));
  return __uint_as_float(__builtin_amdgcn_readlane(__float_as_uint(x), 63));
}
__device__ __forceinline__ float lanebcast(float x, int l) {
  return __uint_as_float(__builtin_amdgcn_readlane(__float_as_uint(x), l));
}

// ---------------------------------------------------------------------------
// Megastep P, blocked-apply version. 1024 threads = 16 waves; wave w owns
// cols {2w, 2w+1} of its panel.
//   role r (P>0): larfb-apply (I - V T^H V^H) of panel P-1 to panel P+r via
//     3 chain-free passes (W = V^H A dots; w2 = T^H W; A -= V w2). sT/sW
//     padded [32][33] -> conflict-free (round-10's 32-way conflict fixed).
//   role 0: then factorize panel P (round-12 code, unchanged), build T_P
//     (zlarft Gram + recurrence), store V->A, T->Tbuf.
//   P==0: role>0 transpose-init panels; role 0 factorizes panel 0 + T_0.
// ---------------------------------------------------------------------------
template<int P>
__global__ __launch_bounds__(1024, 1) void qr_megastep(
    const float* __restrict__ ure_raw, const float* __restrict__ uim_raw,
    float2* __restrict__ A, float2* __restrict__ tau,
    float2* __restrict__ Tbuf)
{
  const int tid = threadIdx.x, lane = tid & 63, w = tid >> 6;   // w 0..15
  const int role = blockIdx.x;
  __shared__ float2 sv32[32][256];
  __shared__ float2 sfin[32][256];
  __shared__ float2 snext[2][256];
  __shared__ float2 sW[32][33];      // padded: stride 264B -> 2-way banks
  __shared__ float2 sT[32][33];
  __shared__ float2 stauOut[32];

  constexpr int J0P  = (P > 0) ? 32*(P-1) : 0;   // prev-panel start
  constexpr int RP   = 256 - J0P;
  constexpr int MCHP = (RP + 63) >> 6;
  constexpr int PIV  = (P == 0) ? 0 : 32;        // pivot row offset in window
  constexpr int J0W  = (P == 0) ? 0 : J0P;       // factorize window start
  constexpr int RW   = 256 - J0W;
  constexpr int MCHW = (RW + 63) >> 6;

  if constexpr (P == 0) {
    if (role > 0) {
      const int c0 = 32*role;
      const int c = tid & 31, r0 = tid >> 5;     // r0 0..31
      #pragma unroll
      for (int r8 = 0; r8 < 8; ++r8) {
        int r = r0 + r8*32;
        A[(size_t)(c0+c)*D_ + r] = make_float2(ure_raw[(size_t)r*D_ + c0 + c],
                                               uim_raw[(size_t)r*D_ + c0 + c]);
      }
      return;
    }
  }

  float2 col[2][4];

  if constexpr (P > 0) {
    // ---- stage V_{P-1}, T_{P-1}, own columns ----
    #pragma unroll
    for (int it = 0; it < 8; ++it) {
      int idx = it*1024 + tid;
      int c = idx >> 8, rr = idx & 255;
      float2 val = make_float2(0.f, 0.f);
      if (rr < RP) val = A[(size_t)(J0P+c)*D_ + J0P + rr];
      sv32[c][rr] = val;
    }
    {
      const float2* Tg = Tbuf + (size_t)(P-1)*1024;
      sT[tid >> 5][tid & 31] = Tg[tid];          // 1024 elements exactly
    }
    const int c0 = (role > 0) ? 32*(P + role) : 32*P;
    #pragma unroll
    for (int lc = 0; lc < 2; ++lc) {
      int cg = c0 + 2*w + lc;
      #pragma unroll
      for (int m = 0; m < 4; ++m) {
        int rr = m*64 + lane;
        col[lc][m] = make_float2(0.f, 0.f);
        if (m < MCHP && rr < RP) col[lc][m] = A[(size_t)cg*D_ + J0P + rr];
      }
    }
    __syncthreads();

    // ---- larfb pass 1: W = V^H a (independent dots, chain-free) ----
    #pragma unroll 4
    for (int k = 0; k < 32; ++k) {
      float2 v[4];
      { float2 rv = sv32[k][lane];
        v[0] = (lane > k) ? rv : ((lane == k) ? make_float2(1.f, 0.f)
                                              : make_float2(0.f, 0.f)); }
      #pragma unroll
      for (int m = 1; m < 4; ++m) v[m] = sv32[k][m*64 + lane];
      #pragma unroll
      for (int lc = 0; lc < 2; ++lc) {
        float wr = 0.f, wi = 0.f;
        #pragma unroll
        for (int m = 0; m < 4; ++m) {
          if (m < MCHP) {
            float2 a = col[lc][m];
            wr += v[m].x*a.x + v[m].y*a.y;       // conj(v)*a
            wi += v[m].x*a.y - v[m].y*a.x;
          }
        }
        wr = wredsum(wr); wi = wredsum(wi);
        if (lane == 0) sW[2*w + lc][k] = make_float2(wr, wi);
      }
    }
    // ---- pass 2: w2 = T^H w (per-col; intra-wave, ordered) ----
    #pragma unroll
    for (int lc = 0; lc < 2; ++lc) {
      int cb = 2*w + lc;
      if (lane < 32) {
        float2 acc = make_float2(0.f, 0.f);
        #pragma unroll 1
        for (int k = 0; k < 32; ++k) {
          float2 t = sT[k][lane];                // conj(T[k][j]), j=lane
          float2 wv = sW[cb][k];
          acc.x += t.x*wv.x + t.y*wv.y;
          acc.y += t.x*wv.y - t.y*wv.x;
        }
        sW[cb][lane] = acc;                      // all reads precede write
      }
    }
    // ---- pass 3: a -= V w2 ----
    #pragma unroll 4
    for (int k = 0; k < 32; ++k) {
      float2 v[4];
      { float2 rv = sv32[k][lane];
        v[0] = (lane > k) ? rv : ((lane == k) ? make_float2(1.f, 0.f)
                                              : make_float2(0.f, 0.f)); }
      #pragma unroll
      for (int m = 1; m < 4; ++m) v[m] = sv32[k][m*64 + lane];
      #pragma unroll
      for (int lc = 0; lc < 2; ++lc) {
        float2 f = sW[2*w + lc][k];
        #pragma unroll
        for (int m = 0; m < 4; ++m) {
          if (m < MCHP) {
            col[lc][m].x -= f.x*v[m].x - f.y*v[m].y;
            col[lc][m].y -= f.x*v[m].y + f.y*v[m].x;
          }
        }
      }
    }

    if (role > 0) {
      #pragma unroll
      for (int lc = 0; lc < 2; ++lc) {
        int cg = 32*(P + role) + 2*w + lc;
        #pragma unroll
        for (int m = 0; m < 4; ++m) {
          int rr = m*64 + lane;
          if (m < MCHP && rr < RP) A[(size_t)cg*D_ + J0P + rr] = col[lc][m];
        }
      }
      return;
    }
    __syncthreads();
  } else {
    // P == 0, role 0: init panel 0 into registers (transposed raw read)
    #pragma unroll
    for (int lc = 0; lc < 2; ++lc) {
      int cg = 2*w + lc;
      #pragma unroll
      for (int m = 0; m < 4; ++m) {
        int rr = m*64 + lane;
        col[lc][m] = make_float2(ure_raw[(size_t)rr*D_ + cg],
                                 uim_raw[(size_t)rr*D_ + cg]);
      }
    }
  }

  // ===== role 0: factorize panel P (round-12 code, unchanged) =====
  if (w == 0) {
    #pragma unroll
    for (int m = 0; m < 4; ++m) snext[0][m*64 + lane] = col[0][m];
  }
  __syncthreads();

  #pragma unroll 1
  for (int jl = 0; jl < 32; ++jl) {
    const int cur = jl & 1, nxt = cur ^ 1;
    float2 pc[4];
    #pragma unroll
    for (int m = 0; m < 4; ++m) pc[m] = snext[cur][m*64 + lane];
    float part = (lane > PIV + jl) ? (pc[0].x*pc[0].x + pc[0].y*pc[0].y) : 0.f;
    if (1 < MCHW) part += pc[1].x*pc[1].x + pc[1].y*pc[1].y;
    if (2 < MCHW) part += pc[2].x*pc[2].x + pc[2].y*pc[2].y;
    if (3 < MCHW) part += pc[3].x*pc[3].x + pc[3].y*pc[3].y;
    part = wredsum(part);
    float ar = lanebcast(pc[0].x, PIV + jl), ai = lanebcast(pc[0].y, PIV + jl);
    float taur, taui, sclr, scli, beta;
    if (part == 0.f && ai == 0.f) {
      taur = taui = sclr = scli = 0.f; beta = ar;      // H = I
    } else {
      float nrm = sqrtf(ar*ar + ai*ai + part);
      beta = (ar >= 0.f) ? -nrm : nrm;                 // -SIGN(nrm, Re(alpha))
      taur = (beta - ar)/beta; taui = -ai/beta;
      float dr = ar - beta, di = ai, dn = dr*dr + di*di;
      sclr = dr/dn; scli = -di/dn;                     // 1/(alpha-beta)
    }
    if (w == 0 && lane == 0) stauOut[jl] = make_float2(taur, taui);
    float2 v[4];
    {
      float2 t0 = make_float2(pc[0].x*sclr - pc[0].y*scli,
                              pc[0].x*scli + pc[0].y*sclr);
      v[0] = (lane > PIV + jl) ? t0 : ((lane == PIV + jl)
                 ? make_float2(1.f, 0.f) : make_float2(0.f, 0.f));
    }
    #pragma unroll
    for (int m = 1; m < 4; ++m)
      v[m] = make_float2(pc[m].x*sclr - pc[m].y*scli,
                         pc[m].x*scli + pc[m].y*sclr);
    if (w == 0) {                          // pivot column -> LDS
      #pragma unroll
      for (int m = 0; m < 4; ++m) {
        int rr = m*64 + lane;
        float2 o = v[m];
        if (m == 0) {
          if (lane < PIV + jl)       o = pc[0];
          else if (lane == PIV + jl) o = make_float2(beta, 0.f);
        }
        if (m < MCHW && rr < RW) sfin[jl][rr] = o;
      }
    }
    #pragma unroll
    for (int lc = 0; lc < 2; ++lc) {
      int cl = 2*w + lc;
      if (cl > jl) {
        float wr, wi;
        { float2 a = col[lc][0];
          wr = v[0].x*a.x + v[0].y*a.y; wi = v[0].x*a.y - v[0].y*a.x; }
        if (1 < MCHW) { float2 a = col[lc][1];
          wr += v[1].x*a.x + v[1].y*a.y; wi += v[1].x*a.y - v[1].y*a.x; }
        if (2 < MCHW) { float2 a = col[lc][2];
          wr += v[2].x*a.x + v[2].y*a.y; wi += v[2].x*a.y - v[2].y*a.x; }
        if (3 < MCHW) { float2 a = col[lc][3];
          wr += v[3].x*a.x + v[3].y*a.y; wi += v[3].x*a.y - v[3].y*a.x; }
        wr = wredsum(wr); wi = wredsum(wi);
        float fr = taur*wr + taui*wi;                  // f = conj(tau)*w
        float fi = taur*wi - taui*wr;
        { col[lc][0].x -= fr*v[0].x - fi*v[0].y;
          col[lc][0].y -= fr*v[0].y + fi*v[0].x; }
        if (1 < MCHW) { col[lc][1].x -= fr*v[1].x - fi*v[1].y;
                        col[lc][1].y -= fr*v[1].y + fi*v[1].x; }
        if (2 < MCHW) { col[lc][2].x -= fr*v[2].x - fi*v[2].y;
                        col[lc][2].y -= fr*v[2].y + fi*v[2].x; }
        if (3 < MCHW) { col[lc][3].x -= fr*v[3].x - fi*v[3].y;
                        col[lc][3].y -= fr*v[3].y + fi*v[3].x; }
        if (cl == jl + 1) {
          #pragma unroll
          for (int m = 0; m < 4; ++m) snext[nxt][m*64 + lane] = col[lc][m];
        }
      }
    }
    __syncthreads();
  }

  // ---- batch-write panel columns + taus ----
  #pragma unroll
  for (int it = 0; it < 8; ++it) {
    int idx = it*1024 + tid;
    int c = idx >> 8, rr = idx & 255;
    if (rr < RW) A[(size_t)(32*P + c)*D_ + J0W + rr] = sfin[c][rr];
  }
  if (tid < 32) tau[32*P + tid] = stauOut[tid];

  // ---- build T_P (zlarft): zero, Gram (16 waves), recurrence (wave 0) ----
  for (int idx = tid; idx < 32*33; idx += 1024) {
    ((float2*)sW)[idx] = make_float2(0.f, 0.f);
    ((float2*)sT)[idx] = make_float2(0.f, 0.f);
  }
  __syncthreads();
  #pragma unroll
  for (int jj = 0; jj < 2; ++jj) {
    int j = w + jj*16;
    for (int i = 0; i < j; ++i) {
      float gr = 0.f, gi = 0.f;
      #pragma unroll
      for (int m = 0; m < 4; ++m) {
        int rr = m*64 + lane;
        if (m < MCHW) {
          float2 vi = sfin[i][rr], vj = sfin[j][rr];
          if (rr > PIV + j && rr < RW) {
            gr += vi.x*vj.x + vi.y*vj.y;               // conj(v_i)*v_j
            gi += vi.x*vj.y - vi.y*vj.x;
          }
        }
      }
      gr = wredsum(gr); gi = wredsum(gi);
      float2 vip = sfin[i][PIV + j];                   // + conj(v_i[piv+j])*1
      gr += vip.x; gi -= vip.y;
      if (lane == 0) sW[i][j] = make_float2(gr, gi);
    }
  }
  __syncthreads();
  if (w == 0) {
    #pragma unroll 1
    for (int j = 0; j < 32; ++j) {
      float2 tj = stauOut[j];
      float2 g = (lane < j) ? sW[lane][j] : make_float2(0.f, 0.f);
      float2 tmp = make_float2(-(tj.x*g.x - tj.y*g.y),
                               -(tj.x*g.y + tj.y*g.x));
      if (lane < j) sW[lane][j] = tmp;
      float2 acc = make_float2(0.f, 0.f);
      for (int k = 0; k < j; ++k) {
        float2 t = sT[lane][k];
        float2 tm = sW[k][j];
        acc.x += t.x*tm.x - t.y*tm.y;
        acc.y += t.x*tm.y + t.y*tm.x;
      }
      if (lane == j)     sT[lane][j] = tj;
      else if (lane < j) sT[lane][j] = acc;
    }
  }
  __syncthreads();
  Tbuf[(size_t)P*1024 + tid] = sT[tid >> 5][tid & 31];
}

// ---------------------------------------------------------------------------
// Blocked zung2r: column c of Q = [panel_0]...[panel_7] e_c where panel_p =
// I - V_p T_p V_p^H; panels with 32p > c are identity on e_c (skipped).
// Per panel: 32 INDEPENDENT dots + 32x32 matvec + 32 axpys — no dependent
// reflector chain (was 256-step serial chain at ~115us). One wave per column.
// ---------------------------------------------------------------------------
__global__ __launch_bounds__(256, 1) void qr_bwd_kernel(
    const float2* __restrict__ A, const float2* __restrict__ Tbuf,
    u16* __restrict__ Benc, u16* __restrict__ Bdec)
{
  const int lane = threadIdx.x & 63;
  const int w = threadIdx.x >> 6;
  const int c = blockIdx.x * 4 + w;          // column 0..255
  __shared__ float2 sT[32][33];
  __shared__ float2 sWb[4][32];

  float2 q[4];
  #pragma unroll
  for (int m = 0; m < 4; ++m) {
    q[m] = make_float2(0.f, 0.f);
    if (m*64 + lane == c) q[m].x = 1.f;      // q = e_c
  }

  #pragma unroll 1
  for (int p = 7; p >= 0; --p) {
    __syncthreads();
    {   // stage T_p (1024 float2, 256 threads x 4)
      const float2* Tg = Tbuf + (size_t)p*1024;
      #pragma unroll
      for (int it = 0; it < 4; ++it) {
        int idx = it*256 + threadIdx.x;
        sT[idx >> 5][idx & 31] = Tg[idx];
      }
    }
    __syncthreads();
    if (32*p > c) continue;                  // identity on this column

    // pass 1: w = V_p^H q (independent dots)
    #pragma unroll 4
    for (int k = 0; k < 32; ++k) {
      int i = 32*p + k;
      float wr = 0.f, wi = 0.f;
      #pragma unroll
      for (int m = 0; m < 4; ++m) {
        int r = m*64 + lane;
        float2 a = A[(size_t)i*D_ + r];
        float2 v = (r > i) ? a : ((r == i) ? make_float2(1.f, 0.f)
                                           : make_float2(0.f, 0.f));
        wr += v.x*q[m].x + v.y*q[m].y;       // conj(v)*q
        wi += v.x*q[m].y - v.y*q[m].x;
      }
      wr = wredsum(wr); wi = wredsum(wi);
      if (lane == 0) sWb[w][k] = make_float2(wr, wi);
    }
    // pass 2: w2 = T w (non-conj; T upper, zeros elsewhere)
    if (lane < 32) {
      float2 acc = make_float2(0.f, 0.f);
      #pragma unroll 1
      for (int k = 0; k < 32; ++k) {
        float2 t = sT[lane][k];
        float2 wk = sWb[w][k];
        acc.x += t.x*wk.x - t.y*wk.y;
        acc.y += t.x*wk.y + t.y*wk.x;
      }
      sWb[w][lane] = acc;                    // all reads precede write
    }
    // pass 3: q -= V w2
    #pragma unroll 4
    for (int k = 0; k < 32; ++k) {
      int i = 32*p + k;
      float2 f = sWb[w][k];
      #pragma unroll
      for (int m = 0; m < 4; ++m) {
        int r = m*64 + lane;
        float2 a = A[(size_t)i*D_ + r];
        float2 v = (r > i) ? a : ((r == i) ? make_float2(1.f, 0.f)
                                           : make_float2(0.f, 0.f));
        q[m].x -= f.x*v.x - f.y*v.y;
        q[m].y -= f.x*v.y + f.y*v.x;
      }
    }
  }

  #pragma unroll
  for (int m = 0; m < 4; ++m) {
    int r = m*64 + lane;
    u16 qre = f2bf(q[m].x), qim = f2bf(q[m].y), qimn = f2bf(-q[m].y);
    Benc[(size_t)c*D_ + r]              = qre;
    Benc[(size_t)(c+256)*D_ + r]        = qim;
    Bdec[(size_t)c*512 + r]             = qre;
    Bdec[(size_t)c*512 + 256 + r]       = qimn;
    Bdec[(size_t)(c+256)*512 + r]       = qim;
    Bdec[(size_t)(c+256)*512 + 256 + r] = qre;
  }
}

// ---------------------------------------------------------------------------
// bf16 MFMA GEMM, 128x128 tile, 4 waves, BK=64, 16x16x32 MFMA.
// encode_gemm reads fp32 x directly and converts during staging.
// ---------------------------------------------------------------------------
#define LDT 72

__global__ __launch_bounds__(256) void encode_gemm(
    const float* __restrict__ x, const u16* __restrict__ Bt,
    u16* __restrict__ xer16, u16* __restrict__ xei16)
{
  __shared__ u16 sA[128*LDT];
  __shared__ u16 sB[128*LDT];
  const int tid = threadIdx.x;
  const int lane = tid & 63, w = tid >> 6;
  const int wr = w >> 1, wc = w & 1;
  const int l15 = lane & 15, l4 = lane >> 4;
  const int m0 = blockIdx.x * 128;
  const int n0 = blockIdx.y * 128;
  f32x4 acc[4][4] = {};
  for (int kb = 0; kb < 4; ++kb) {
    #pragma unroll
    for (int i = 0; i < 4; ++i) {
      int chunk = i*256 + tid;
      int row = chunk >> 3, k0 = (chunk & 7) * 8;
      const float* xs = x + (size_t)(m0+row)*D_ + kb*64 + k0;
      float4 f0 = *(const float4*)xs;
      float4 f1 = *(const float4*)(xs + 4);
      int4 va;
      va.x = (int)((unsigned)f2bf(f0.x) | ((unsigned)f2bf(f0.y) << 16));
      va.y = (int)((unsigned)f2bf(f0.z) | ((unsigned)f2bf(f0.w) << 16));
      va.z = (int)((unsigned)f2bf(f1.x) | ((unsigned)f2bf(f1.y) << 16));
      va.w = (int)((unsigned)f2bf(f1.z) | ((unsigned)f2bf(f1.w) << 16));
      int4 vb = *(const int4*)(Bt + (size_t)(n0+row)*D_ + kb*64 + k0);
      *(int4*)&sA[row*LDT + k0] = va;
      *(int4*)&sB[row*LDT + k0] = vb;
    }
    __syncthreads();
    #pragma unroll
    for (int ks = 0; ks < 2; ++ks) {
      bf16x8 af[4], bb[4];
      #pragma unroll
      for (int mf = 0; mf < 4; ++mf)
        af[mf] = *(const bf16x8*)&sA[(wr*64 + mf*16 + l15)*LDT + ks*32 + l4*8];
      #pragma unroll
      for (int nf = 0; nf < 4; ++nf)
        bb[nf] = *(const bf16x8*)&sB[(wc*64 + nf*16 + l15)*LDT + ks*32 + l4*8];
      #pragma unroll
      for (int mf = 0; mf < 4; ++mf)
        #pragma unroll
        for (int nf = 0; nf < 4; ++nf)
          acc[mf][nf] = __builtin_amdgcn_mfma_f32_16x16x32_bf16(
              af[mf], bb[nf], acc[mf][nf], 0, 0, 0);
    }
    __syncthreads();
  }
  #pragma unroll
  for (int mf = 0; mf < 4; ++mf)
    #pragma unroll
    for (int nf = 0; nf < 4; ++nf)
      #pragma unroll
      for (int r = 0; r < 4; ++r) {
        int row = m0 + wr*64 + mf*16 + l4*4 + r;
        int col = n0 + wc*64 + nf*16 + l15;
        float v = acc[mf][nf][r];
        if (col < 256) xer16[(size_t)row*D_ + col] = f2bf(v);
        else           xei16[(size_t)row*D_ + col - 256] = f2bf(-v);
      }
}

__global__ __launch_bounds__(256) void decode_gemm(
    const u16* __restrict__ hre16, const u16* __restrict__ him16,
    const u16* __restrict__ Bt, float* __restrict__ out)
{
  __shared__ u16 sA[128*LDT];
  __shared__ u16 sB[128*LDT];
  const int tid = threadIdx.x;
  const int lane = tid & 63, w = tid >> 6;
  const int wr = w >> 1, wc = w & 1;
  const int l15 = lane & 15, l4 = lane >> 4;
  const int m0 = blockIdx.x * 128;
  const int n0 = blockIdx.y * 128;
  f32x4 acc[4][4] = {};
  for (int kb = 0; kb < 8; ++kb) {
    const u16* aplane = (kb < 4) ? hre16 : him16;
    const int kk = (kb & 3) * 64;
    #pragma unroll
    for (int i = 0; i < 4; ++i) {
      int chunk = i*256 + tid;
      int row = chunk >> 3, k0 = (chunk & 7) * 8;
      int4 va = *(const int4*)(aplane + (size_t)(m0+row)*D_ + kk + k0);
      int4 vb = *(const int4*)(Bt + (size_t)(n0+row)*512 + kb*64 + k0);
      *(int4*)&sA[row*LDT + k0] = va;
      *(int4*)&sB[row*LDT + k0] = vb;
    }
    __syncthreads();
    #pragma unroll
    for (int ks = 0; ks < 2; ++ks) {
      bf16x8 af[4], bb[4];
      #pragma unroll
      for (int mf = 0; mf < 4; ++mf)
        af[mf] = *(const bf16x8*)&sA[(wr*64 + mf*16 + l15)*LDT + ks*32 + l4*8];
      #pragma unroll
      for (int nf = 0; nf < 4; ++nf)
        bb[nf] = *(const bf16x8*)&sB[(wc*64 + nf*16 + l15)*LDT + ks*32 + l4*8];
      #pragma unroll
      for (int mf = 0; mf < 4; ++mf)
        #pragma unroll
        for (int nf = 0; nf < 4; ++nf)
          acc[mf][nf] = __builtin_amdgcn_mfma_f32_16x16x32_bf16(
              af[mf], bb[nf], acc[mf][nf], 0, 0, 0);
    }
    __syncthreads();
  }
  #pragma unroll
  for (int mf = 0; mf < 4; ++mf)
    #pragma unroll
    for (int nf = 0; nf < 4; ++nf)
      #pragma unroll
      for (int r = 0; r < 4; ++r) {
        int row = m0 + wr*64 + mf*16 + l4*4 + r;
        int col = n0 + wc*64 + nf*16 + l15;
        float v = acc[mf][nf][r];
        if (col < 256) out[(size_t)row*D_ + col] = v;
        else           out[PLANE + (size_t)row*D_ + col - 256] = v;
      }
}

// ---------------------------------------------------------------------------
// Scan with fused coefficient computation. One block per (b,n); thread = d.
// ---------------------------------------------------------------------------
__global__ __launch_bounds__(256) void scan_kernel(
  const float* __restrict__ eps, const float* __restrict__ dt,
  const float* __restrict__ lam_re, const float* __restrict__ lam_im,
  const float* __restrict__ noise_raw,
  const u16* __restrict__ xer16, const u16* __restrict__ xei16,
  u16* __restrict__ hre16, u16* __restrict__ him16)
{
  int bx = blockIdx.x;
  int b = bx >> 9, n = bx & 511;
  int d = threadIdx.x;
  __shared__ float sdt[T_];
  if (d < T_) sdt[d] = dt[b*T_ + d];
  __syncthreads();

  float lr = lam_re[d], li = lam_im[d];
  float lam_r = fmaxf(-log1pf(expf(-lr)), -0.3f);     // -softplus(-x), clamp
  float t0 = lam_r + 1e-12f;
  float sgn = (t0 > 0.f) ? 1.f : ((t0 < 0.f) ? -1.f : 0.f);
  float den_re = lam_r + 1e-8f*sgn, den_im = li;      // lam_safe
  float d2 = den_re*den_re + den_im*den_im;
  float nsc = log1pf(expf(noise_raw[d])) * 0.01f;

  float hr = 0.f, hi = 0.f;
  for (int t = 0; t < T_; ++t) {
    float dtv = sdt[t];
    float er = expf(dtv*lam_r);
    float ai = dtv*li;
    float dre = er*cosf(ai), dim_ = er*sinf(ai);
    float nr = dre - 1.f, ni = dim_;
    float fre = (nr*den_re + ni*den_im)/d2;
    float fim = (ni*den_re - nr*den_im)/d2;
    float ns = sqrtf(fmaxf(dtv, 0.f)) * nsc;
    size_t idx = ((size_t)(b*T_ + t)*N_ + n)*D_ + d;
    float xr = bf2f(xer16[idx]), xi = bf2f(xei16[idx]), ep = eps[idx];
    float br = fre*xr - fim*xi + ep*ns;
    float bi = fre*xi + fim*xr;
    float nr2 = dre*hr - dim_*hi + br;
    float ni2 = dre*hi + dim_*hr + bi;
    hr = nr2; hi = ni2;
    hre16[idx] = f2bf(hr); him16[idx] = f2bf(hi);
  }
}

// ---------------------------------------------------------------------------
extern "C" void kernel_launch(void* const* d_in, const int* in_sizes, int n_in,
                              void* d_out, int out_size, void* d_ws, size_t ws_size,
                              hipStream_t stream)
{
  const float* x         = (const float*)d_in[0];
  const float* dt        = (const float*)d_in[1];
  const float* eps       = (const float*)d_in[2];
  const float* ure_raw   = (const float*)d_in[3];
  const float* uim_raw   = (const float*)d_in[4];
  const float* lam_re    = (const float*)d_in[5];
  const float* lam_im    = (const float*)d_in[6];
  const float* noise_raw = (const float*)d_in[7];
  float* out = (float*)d_out;

  // ws layout (132 MB total):
  //   0       A float2[65536]            512 KB
  //   512K    tau float2[256]            2 KB
  //   640K    Tbuf float2[8*1024]        64 KB
  //   1M      Benc bf16 [512][256]       256 KB
  //   1.5M    Bdec bf16 [512][512]       512 KB
  //   4M      hre16 bf16 [M][256] 32 MB
  //   36M     xer16 32 MB
  //   68M     xei16 32 MB
  //   100M    him16 32 MB
  char* ws = (char*)d_ws;
  float2* A    = (float2*)(ws);
  float2* tau  = (float2*)(ws + 524288);
  float2* Tbuf = (float2*)(ws + 655360);
  u16* Benc    = (u16*)(ws + (1<<20));
  u16* Bdec    = (u16*)(ws + 1572864);
  u16* hre16   = (u16*)(ws + ((size_t)4<<20));
  u16* xer16   = (u16*)(ws + ((size_t)36<<20));
  u16* xei16   = (u16*)(ws + ((size_t)68<<20));
  u16* him16   = (u16*)(ws + ((size_t)100<<20));

  qr_megastep<0><<<8, 1024, 0, stream>>>(ure_raw, uim_raw, A, tau, Tbuf);
  qr_megastep<1><<<7, 1024, 0, stream>>>(ure_raw, uim_raw, A, tau, Tbuf);
  qr_megastep<2><<<6, 1024, 0, stream>>>(ure_raw, uim_raw, A, tau, Tbuf);
  qr_megastep<3><<<5, 1024, 0, stream>>>(ure_raw, uim_raw, A, tau, Tbuf);
  qr_megastep<4><<<4, 1024, 0, stream>>>(ure_raw, uim_raw, A, tau, Tbuf);
  qr_megastep<5><<<3, 1024, 0, stream>>>(ure_raw, uim_raw, A, tau, Tbuf);
  qr_megastep<6><<<2, 1024, 0, stream>>>(ure_raw, uim_raw, A, tau, Tbuf);
  qr_megastep<7><<<1, 1024, 0, stream>>>(ure_raw, uim_raw, A, tau, Tbuf);
  qr_bwd_kernel<<<64, 256, 0, stream>>>(A, Tbuf, Benc, Bdec);
  encode_gemm<<<dim3(M_/128, 4), 256, 0, stream>>>(x, Benc, xer16, xei16);
  scan_kernel<<<B_*N_, 256, 0, stream>>>(eps, dt, lam_re, lam_im, noise_raw,
                                         xer16, xei16, hre16, him16);
  decode_gemm<<<dim3(M_/128, 4), 256, 0, stream>>>(hre16, him16, Bdec, out);
}

// Round 14
// 749.550 us; speedup vs baseline: 1.7498x; 1.7498x over previous
//
#include <hip/hip_runtime.h>
#include <math.h>

// Problem constants (B,T,N,D) = (2,64,512,256)
#define B_ 2
#define T_ 64
#define N_ 512
#define D_ 256
#define M_ (B_*T_*N_)            // 65536 rows for the GEMMs
#define PLANE ((size_t)M_*D_)    // 16777216 elements per output plane

typedef unsigned short u16;
typedef __attribute__((ext_vector_type(8))) short bf16x8;
typedef __attribute__((ext_vector_type(4))) float f32x4;

__device__ __forceinline__ u16 f2bf(float f) {
  union { float f; unsigned u; } cv; cv.f = f;
  unsigned u = cv.u;
  return (u16)((u + 0x7FFFu + ((u >> 16) & 1u)) >> 16);   // RNE
}
__device__ __forceinline__ float bf2f(u16 h) {
  union { unsigned u; float f; } cv; cv.u = ((unsigned)h) << 16;
  return cv.f;
}

// 64-lane sum via DPP (VALU-only). Result wave-uniform via readlane 63.
__device__ __forceinline__ float wredsum(float x) {
  x += __uint_as_float(__builtin_amdgcn_update_dpp(0u, __float_as_uint(x), 0x111, 0xf, 0xf, true));
  x += __uint_as_float(__builtin_amdgcn_update_dpp(0u, __float_as_uint(x), 0x112, 0xf, 0xf, true));
  x += __uint_as_float(__builtin_amdgcn_update_dpp(0u, __float_as_uint(x), 0x114, 0xf, 0xf, true));
  x += __uint_as_float(__builtin_amdgcn_update_dpp(0u, __float_as_uint(x), 0x118, 0xf, 0xf, true));
  x += __uint_as_float(__builtin_amdgcn_update_dpp(0u, __float_as_uint(x), 0x142, 0xa, 0xf, true));
  x += __uint_as_float(__builtin_amdgcn_update_dpp(0u, __float_as_uint(x), 0x143, 0xc, 0xf, true));
  return __uint_as_float(__builtin_amdgcn_readlane(__float_as_uint(x), 63));
}
__device__ __forceinline__ float lanebcast(float x, int l) {
  return __uint_as_float(__builtin_amdgcn_readlane(__float_as_uint(x), l));
}

// ---------------------------------------------------------------------------
// Megastep P (r12 structure + owner-precompute factorize). 1024 threads =
// 16 waves; wave w owns cols {2w, 2w+1}.
//   role 0:   (P>0: chain-apply V_{P-1} to panel P's 32 cols), factorize P.
//   role r>0: P==0: transpose-init panel r; P>0: apply V_{P-1} to panel P+r.
// Factorize: the wave owning column jl+1 computes the NEXT reflector (norm,
// tau, PRE-SCALED v) right after updating its column — at the tail of step
// jl, overlapped with other waves' updates — and publishes {v,tau} via LDS.
// Other waves never touch pivot math (r12 replicated it 16x at the head of
// every step's critical path). Same float ops, same order -> bit-identical.
// ---------------------------------------------------------------------------
template<int P>
__global__ __launch_bounds__(1024, 1) void qr_megastep(
    const float* __restrict__ ure_raw, const float* __restrict__ uim_raw,
    float2* __restrict__ A, float2* __restrict__ tau)
{
  const int tid = threadIdx.x, lane = tid & 63, w = tid >> 6;   // w 0..15
  const int role = blockIdx.x;
  __shared__ float2 sv32[32][256];
  __shared__ float2 sfin[32][256];
  __shared__ float2 snext[2][256];
  __shared__ float2 stau2[2];
  __shared__ float2 stau32[32];
  __shared__ float2 stauOut[32];

  constexpr int J0P  = (P > 0) ? 32*(P-1) : 0;   // prev-panel start
  constexpr int RP   = 256 - J0P;
  constexpr int MCHP = (RP + 63) >> 6;
  constexpr int PIV  = (P == 0) ? 0 : 32;        // pivot row offset in window
  constexpr int J0W  = (P == 0) ? 0 : J0P;       // factorize window start
  constexpr int RW   = 256 - J0W;
  constexpr int MCHW = (RW + 63) >> 6;

  if constexpr (P == 0) {
    if (role > 0) {
      const int c0 = 32*role;
      const int c = tid & 31, r0 = tid >> 5;     // r0 0..31
      #pragma unroll
      for (int r8 = 0; r8 < 8; ++r8) {
        int r = r0 + r8*32;
        A[(size_t)(c0+c)*D_ + r] = make_float2(ure_raw[(size_t)r*D_ + c0 + c],
                                               uim_raw[(size_t)r*D_ + c0 + c]);
      }
      return;
    }
  }

  float2 col[2][4];

  if constexpr (P > 0) {
    // ---- stage V_{P-1} and taus; load own cols ----
    #pragma unroll
    for (int it = 0; it < 8; ++it) {
      int idx = it*1024 + tid;
      int c = idx >> 8, rr = idx & 255;
      float2 val = make_float2(0.f, 0.f);
      if (rr < RP) val = A[(size_t)(J0P+c)*D_ + J0P + rr];
      sv32[c][rr] = val;
    }
    if (tid < 32) stau32[tid] = tau[J0P + tid];
    const int c0 = (role > 0) ? 32*(P + role) : 32*P;
    #pragma unroll
    for (int lc = 0; lc < 2; ++lc) {
      int cg = c0 + 2*w + lc;
      #pragma unroll
      for (int m = 0; m < 4; ++m) {
        int rr = m*64 + lane;
        col[lc][m] = make_float2(0.f, 0.f);
        if (m < MCHP && rr < RP) col[lc][m] = A[(size_t)cg*D_ + J0P + rr];
      }
    }
    __syncthreads();

    // ---- fused reflector apply: 32 dependent steps, 2 cols/wave ----
    #pragma unroll 4
    for (int jl = 0; jl < 32; ++jl) {
      float2 tt = stau32[jl];
      float2 v[4];
      { float2 rv = sv32[jl][lane];
        v[0] = (lane > jl) ? rv : ((lane == jl) ? make_float2(1.f, 0.f)
                                                : make_float2(0.f, 0.f)); }
      #pragma unroll
      for (int m = 1; m < 4; ++m) v[m] = sv32[jl][m*64 + lane];
      float wr[2], wi[2];
      #pragma unroll
      for (int lc = 0; lc < 2; ++lc) {
        wr[lc] = 0.f; wi[lc] = 0.f;
        #pragma unroll
        for (int m = 0; m < 4; ++m) {
          if (m < MCHP) {
            float2 a = col[lc][m];
            wr[lc] += v[m].x*a.x + v[m].y*a.y;   // conj(v)*a
            wi[lc] += v[m].x*a.y - v[m].y*a.x;
          }
        }
      }
      #pragma unroll
      for (int lc = 0; lc < 2; ++lc) { wr[lc] = wredsum(wr[lc]);
                                       wi[lc] = wredsum(wi[lc]); }
      #pragma unroll
      for (int lc = 0; lc < 2; ++lc) {
        float fr = tt.x*wr[lc] + tt.y*wi[lc];    // f = conj(tau)*w
        float fi = tt.x*wi[lc] - tt.y*wr[lc];
        #pragma unroll
        for (int m = 0; m < 4; ++m) {
          if (m < MCHP) {
            col[lc][m].x -= fr*v[m].x - fi*v[m].y;
            col[lc][m].y -= fr*v[m].y + fi*v[m].x;
          }
        }
      }
    }

    if (role > 0) {
      #pragma unroll
      for (int lc = 0; lc < 2; ++lc) {
        int cg = 32*(P + role) + 2*w + lc;
        #pragma unroll
        for (int m = 0; m < 4; ++m) {
          int rr = m*64 + lane;
          if (m < MCHP && rr < RP) A[(size_t)cg*D_ + J0P + rr] = col[lc][m];
        }
      }
      return;
    }
    __syncthreads();
  } else {
    // P == 0, role 0: init panel 0 into registers (transposed raw read)
    #pragma unroll
    for (int lc = 0; lc < 2; ++lc) {
      int cg = 2*w + lc;
      #pragma unroll
      for (int m = 0; m < 4; ++m) {
        int rr = m*64 + lane;
        col[lc][m] = make_float2(ure_raw[(size_t)rr*D_ + cg],
                                 uim_raw[(size_t)rr*D_ + cg]);
      }
    }
  }

  // ===== role 0: factorize panel P, owner-precompute pipeline =====
  // Prologue: wave 0 (owns col 0) produces reflector 0 -> snext[0]/stau2[0].
  if (w == 0) {
    float part = (lane > PIV) ? (col[0][0].x*col[0][0].x + col[0][0].y*col[0][0].y) : 0.f;
    if (1 < MCHW) part += col[0][1].x*col[0][1].x + col[0][1].y*col[0][1].y;
    if (2 < MCHW) part += col[0][2].x*col[0][2].x + col[0][2].y*col[0][2].y;
    if (3 < MCHW) part += col[0][3].x*col[0][3].x + col[0][3].y*col[0][3].y;
    part = wredsum(part);
    float ar = lanebcast(col[0][0].x, PIV), ai = lanebcast(col[0][0].y, PIV);
    float tr, ti, sr, si, bt;
    if (part == 0.f && ai == 0.f) {
      tr = ti = sr = si = 0.f; bt = ar;                // H = I
    } else {
      float nrm = sqrtf(ar*ar + ai*ai + part);
      bt = (ar >= 0.f) ? -nrm : nrm;                   // -SIGN(nrm, Re(alpha))
      tr = (bt - ar)/bt; ti = -ai/bt;
      float dr = ar - bt, di = ai, dn = dr*dr + di*di;
      sr = dr/dn; si = -di/dn;                         // 1/(alpha-beta)
    }
    if (lane == 0) { stau2[0] = make_float2(tr, ti);
                     stauOut[0] = make_float2(tr, ti); }
    float2 nv0 = make_float2(col[0][0].x*sr - col[0][0].y*si,
                             col[0][0].x*si + col[0][0].y*sr);
    nv0 = (lane > PIV) ? nv0 : ((lane == PIV) ? make_float2(1.f, 0.f)
                                              : make_float2(0.f, 0.f));
    float2 nv1 = make_float2(col[0][1].x*sr - col[0][1].y*si,
                             col[0][1].x*si + col[0][1].y*sr);
    float2 nv2 = make_float2(col[0][2].x*sr - col[0][2].y*si,
                             col[0][2].x*si + col[0][2].y*sr);
    float2 nv3 = make_float2(col[0][3].x*sr - col[0][3].y*si,
                             col[0][3].x*si + col[0][3].y*sr);
    snext[0][lane]       = nv0;
    snext[0][64 + lane]  = nv1;
    snext[0][128 + lane] = nv2;
    snext[0][192 + lane] = nv3;
    float2 o0 = (lane < PIV) ? col[0][0]
              : ((lane == PIV) ? make_float2(bt, 0.f) : nv0);
    sfin[0][lane] = o0;
    if (1 < MCHW) sfin[0][64 + lane]  = nv1;
    if (2 < MCHW) sfin[0][128 + lane] = nv2;
    if (3 < MCHW) sfin[0][192 + lane] = nv3;
  }
  __syncthreads();

  #pragma unroll 1
  for (int jl = 0; jl < 31; ++jl) {            // step 31 would update nothing
    const int cur = jl & 1, nxt = cur ^ 1;
    float2 v0 = snext[cur][lane],      v1 = snext[cur][64 + lane],
           v2 = snext[cur][128 + lane], v3 = snext[cur][192 + lane];
    float2 tt = stau2[cur];                    // LDS broadcast
    #pragma unroll
    for (int lc = 0; lc < 2; ++lc) {
      int cl = 2*w + lc;
      if (cl > jl) {
        float wr, wi;
        { float2 a = col[lc][0];
          wr = v0.x*a.x + v0.y*a.y; wi = v0.x*a.y - v0.y*a.x; }
        if (1 < MCHW) { float2 a = col[lc][1];
          wr += v1.x*a.x + v1.y*a.y; wi += v1.x*a.y - v1.y*a.x; }
        if (2 < MCHW) { float2 a = col[lc][2];
          wr += v2.x*a.x + v2.y*a.y; wi += v2.x*a.y - v2.y*a.x; }
        if (3 < MCHW) { float2 a = col[lc][3];
          wr += v3.x*a.x + v3.y*a.y; wi += v3.x*a.y - v3.y*a.x; }
        wr = wredsum(wr); wi = wredsum(wi);
        float fr = tt.x*wr + tt.y*wi;          // f = conj(tau)*w
        float fi = tt.x*wi - tt.y*wr;
        { col[lc][0].x -= fr*v0.x - fi*v0.y;
          col[lc][0].y -= fr*v0.y + fi*v0.x; }
        if (1 < MCHW) { col[lc][1].x -= fr*v1.x - fi*v1.y;
                        col[lc][1].y -= fr*v1.y + fi*v1.x; }
        if (2 < MCHW) { col[lc][2].x -= fr*v2.x - fi*v2.y;
                        col[lc][2].y -= fr*v2.y + fi*v2.x; }
        if (3 < MCHW) { col[lc][3].x -= fr*v3.x - fi*v3.y;
                        col[lc][3].y -= fr*v3.y + fi*v3.x; }
        if (cl == jl + 1) {
          // owner: produce reflector jl+1 from the just-updated column
          const int pr = PIV + jl + 1;         // pivot row, always chunk 0
          float part = (lane > pr) ? (col[lc][0].x*col[lc][0].x +
                                      col[lc][0].y*col[lc][0].y) : 0.f;
          if (1 < MCHW) part += col[lc][1].x*col[lc][1].x + col[lc][1].y*col[lc][1].y;
          if (2 < MCHW) part += col[lc][2].x*col[lc][2].x + col[lc][2].y*col[lc][2].y;
          if (3 < MCHW) part += col[lc][3].x*col[lc][3].x + col[lc][3].y*col[lc][3].y;
          part = wredsum(part);
          float ar = lanebcast(col[lc][0].x, pr), ai = lanebcast(col[lc][0].y, pr);
          float tr, ti, sr, si, bt;
          if (part == 0.f && ai == 0.f) {
            tr = ti = sr = si = 0.f; bt = ar;          // H = I
          } else {
            float nrm = sqrtf(ar*ar + ai*ai + part);
            bt = (ar >= 0.f) ? -nrm : nrm;             // -SIGN(nrm, Re(alpha))
            tr = (bt - ar)/bt; ti = -ai/bt;
            float dr = ar - bt, di = ai, dn = dr*dr + di*di;
            sr = dr/dn; si = -di/dn;                   // 1/(alpha-beta)
          }
          if (lane == 0) { stau2[nxt] = make_float2(tr, ti);
                           stauOut[jl+1] = make_float2(tr, ti); }
          float2 m0v = make_float2(col[lc][0].x*sr - col[lc][0].y*si,
                                   col[lc][0].x*si + col[lc][0].y*sr);
          m0v = (lane > pr) ? m0v : ((lane == pr) ? make_float2(1.f, 0.f)
                                                  : make_float2(0.f, 0.f));
          float2 m1v = make_float2(col[lc][1].x*sr - col[lc][1].y*si,
                                   col[lc][1].x*si + col[lc][1].y*sr);
          float2 m2v = make_float2(col[lc][2].x*sr - col[lc][2].y*si,
                                   col[lc][2].x*si + col[lc][2].y*sr);
          float2 m3v = make_float2(col[lc][3].x*sr - col[lc][3].y*si,
                                   col[lc][3].x*si + col[lc][3].y*sr);
          snext[nxt][lane]       = m0v;
          snext[nxt][64 + lane]  = m1v;
          snext[nxt][128 + lane] = m2v;
          snext[nxt][192 + lane] = m3v;
          float2 o0 = (lane < pr) ? col[lc][0]
                    : ((lane == pr) ? make_float2(bt, 0.f) : m0v);
          sfin[jl+1][lane] = o0;
          if (1 < MCHW) sfin[jl+1][64 + lane]  = m1v;
          if (2 < MCHW) sfin[jl+1][128 + lane] = m2v;
          if (3 < MCHW) sfin[jl+1][192 + lane] = m3v;
        }
      }
    }
    __syncthreads();
  }

  // ---- batch-write panel columns + taus to global ----
  #pragma unroll
  for (int it = 0; it < 8; ++it) {
    int idx = it*1024 + tid;
    int c = idx >> 8, rr = idx & 255;
    if (rr < RW) A[(size_t)(32*P + c)*D_ + J0W + rr] = sfin[c][rr];
  }
  if (tid < 32) tau[32*P + tid] = stauOut[tid];
}

// ---------------------------------------------------------------------------
// zung2r: column c of Q = H_0(...H_c(e_c)); one wave per column; depth-2
// register prefetch; DPP reduce (r12 version, measured <=94us).
// Epilogue writes bf16 B^T matrices for both GEMMs.
// ---------------------------------------------------------------------------
__global__ __launch_bounds__(256, 1) void qr_bwd_kernel(
    const float2* __restrict__ A, const float2* __restrict__ tau,
    u16* __restrict__ Benc, u16* __restrict__ Bdec)
{
  const int lane = threadIdx.x & 63;
  const int w = threadIdx.x >> 6;
  const int c = blockIdx.x * 4 + w;          // column 0..255
  __shared__ float2 stau[256];
  if (threadIdx.x < 256) stau[threadIdx.x] = tau[threadIdx.x];
  __syncthreads();

  float2 q[4];
  #pragma unroll
  for (int m = 0; m < 4; ++m) {
    q[m] = make_float2(0.f, 0.f);
    if (m*64 + lane == c) q[m].x = 1.f;      // q = e_c
  }
  float2 a0[4], a1[4];
  #pragma unroll
  for (int m = 0; m < 4; ++m) a0[m] = A[(size_t)c*D_ + m*64 + lane];
  {
    int i1 = (c >= 1) ? c - 1 : 0;
    #pragma unroll
    for (int m = 0; m < 4; ++m) a1[m] = A[(size_t)i1*D_ + m*64 + lane];
  }

  #pragma unroll 1
  for (int i = c; i >= 0; --i) {
    int ip = (i >= 2) ? i - 2 : 0;
    float2 a2[4];
    #pragma unroll
    for (int m = 0; m < 4; ++m) a2[m] = A[(size_t)ip*D_ + m*64 + lane];

    float2 tt = stau[i];
    float2 v[4];
    #pragma unroll
    for (int m = 0; m < 4; ++m) {
      int r = m*64 + lane;
      v[m] = (r > i) ? a0[m] : ((r == i) ? make_float2(1.f, 0.f)
                                         : make_float2(0.f, 0.f));
    }
    float wr = 0.f, wi = 0.f;
    #pragma unroll
    for (int m = 0; m < 4; ++m) {
      wr += v[m].x*q[m].x + v[m].y*q[m].y;   // w += conj(v)*q
      wi += v[m].x*q[m].y - v[m].y*q[m].x;
    }
    wr = wredsum(wr); wi = wredsum(wi);
    float fr = tt.x*wr - tt.y*wi;            // f = tau*w (0 when tau==0)
    float fi = tt.x*wi + tt.y*wr;
    #pragma unroll
    for (int m = 0; m < 4; ++m) {
      q[m].x -= fr*v[m].x - fi*v[m].y;
      q[m].y -= fr*v[m].y + fi*v[m].x;
      a0[m] = a1[m]; a1[m] = a2[m];
    }
  }

  #pragma unroll
  for (int m = 0; m < 4; ++m) {
    int r = m*64 + lane;
    u16 qre = f2bf(q[m].x), qim = f2bf(q[m].y), qimn = f2bf(-q[m].y);
    Benc[(size_t)c*D_ + r]              = qre;
    Benc[(size_t)(c+256)*D_ + r]        = qim;
    Bdec[(size_t)c*512 + r]             = qre;
    Bdec[(size_t)c*512 + 256 + r]       = qimn;
    Bdec[(size_t)(c+256)*512 + r]       = qim;
    Bdec[(size_t)(c+256)*512 + 256 + r] = qre;
  }
}

// ---------------------------------------------------------------------------
// bf16 MFMA GEMM, 128x128 tile, 4 waves, BK=64, 16x16x32 MFMA.
// encode_gemm reads fp32 x directly and converts during staging.
// ---------------------------------------------------------------------------
#define LDT 72

__global__ __launch_bounds__(256) void encode_gemm(
    const float* __restrict__ x, const u16* __restrict__ Bt,
    u16* __restrict__ xer16, u16* __restrict__ xei16)
{
  __shared__ u16 sA[128*LDT];
  __shared__ u16 sB[128*LDT];
  const int tid = threadIdx.x;
  const int lane = tid & 63, w = tid >> 6;
  const int wr = w >> 1, wc = w & 1;
  const int l15 = lane & 15, l4 = lane >> 4;
  const int m0 = blockIdx.x * 128;
  const int n0 = blockIdx.y * 128;
  f32x4 acc[4][4] = {};
  for (int kb = 0; kb < 4; ++kb) {
    #pragma unroll
    for (int i = 0; i < 4; ++i) {
      int chunk = i*256 + tid;
      int row = chunk >> 3, k0 = (chunk & 7) * 8;
      const float* xs = x + (size_t)(m0+row)*D_ + kb*64 + k0;
      float4 f0 = *(const float4*)xs;
      float4 f1 = *(const float4*)(xs + 4);
      int4 va;
      va.x = (int)((unsigned)f2bf(f0.x) | ((unsigned)f2bf(f0.y) << 16));
      va.y = (int)((unsigned)f2bf(f0.z) | ((unsigned)f2bf(f0.w) << 16));
      va.z = (int)((unsigned)f2bf(f1.x) | ((unsigned)f2bf(f1.y) << 16));
      va.w = (int)((unsigned)f2bf(f1.z) | ((unsigned)f2bf(f1.w) << 16));
      int4 vb = *(const int4*)(Bt + (size_t)(n0+row)*D_ + kb*64 + k0);
      *(int4*)&sA[row*LDT + k0] = va;
      *(int4*)&sB[row*LDT + k0] = vb;
    }
    __syncthreads();
    #pragma unroll
    for (int ks = 0; ks < 2; ++ks) {
      bf16x8 af[4], bb[4];
      #pragma unroll
      for (int mf = 0; mf < 4; ++mf)
        af[mf] = *(const bf16x8*)&sA[(wr*64 + mf*16 + l15)*LDT + ks*32 + l4*8];
      #pragma unroll
      for (int nf = 0; nf < 4; ++nf)
        bb[nf] = *(const bf16x8*)&sB[(wc*64 + nf*16 + l15)*LDT + ks*32 + l4*8];
      #pragma unroll
      for (int mf = 0; mf < 4; ++mf)
        #pragma unroll
        for (int nf = 0; nf < 4; ++nf)
          acc[mf][nf] = __builtin_amdgcn_mfma_f32_16x16x32_bf16(
              af[mf], bb[nf], acc[mf][nf], 0, 0, 0);
    }
    __syncthreads();
  }
  #pragma unroll
  for (int mf = 0; mf < 4; ++mf)
    #pragma unroll
    for (int nf = 0; nf < 4; ++nf)
      #pragma unroll
      for (int r = 0; r < 4; ++r) {
        int row = m0 + wr*64 + mf*16 + l4*4 + r;
        int col = n0 + wc*64 + nf*16 + l15;
        float v = acc[mf][nf][r];
        if (col < 256) xer16[(size_t)row*D_ + col] = f2bf(v);
        else           xei16[(size_t)row*D_ + col - 256] = f2bf(-v);
      }
}

__global__ __launch_bounds__(256) void decode_gemm(
    const u16* __restrict__ hre16, const u16* __restrict__ him16,
    const u16* __restrict__ Bt, float* __restrict__ out)
{
  __shared__ u16 sA[128*LDT];
  __shared__ u16 sB[128*LDT];
  const int tid = threadIdx.x;
  const int lane = tid & 63, w = tid >> 6;
  const int wr = w >> 1, wc = w & 1;
  const int l15 = lane & 15, l4 = lane >> 4;
  const int m0 = blockIdx.x * 128;
  const int n0 = blockIdx.y * 128;
  f32x4 acc[4][4] = {};
  for (int kb = 0; kb < 8; ++kb) {
    const u16* aplane = (kb < 4) ? hre16 : him16;
    const int kk = (kb & 3) * 64;
    #pragma unroll
    for (int i = 0; i < 4; ++i) {
      int chunk = i*256 + tid;
      int row = chunk >> 3, k0 = (chunk & 7) * 8;
      int4 va = *(const int4*)(aplane + (size_t)(m0+row)*D_ + kk + k0);
      int4 vb = *(const int4*)(Bt + (size_t)(n0+row)*512 + kb*64 + k0);
      *(int4*)&sA[row*LDT + k0] = va;
      *(int4*)&sB[row*LDT + k0] = vb;
    }
    __syncthreads();
    #pragma unroll
    for (int ks = 0; ks < 2; ++ks) {
      bf16x8 af[4], bb[4];
      #pragma unroll
      for (int mf = 0; mf < 4; ++mf)
        af[mf] = *(const bf16x8*)&sA[(wr*64 + mf*16 + l15)*LDT + ks*32 + l4*8];
      #pragma unroll
      for (int nf = 0; nf < 4; ++nf)
        bb[nf] = *(const bf16x8*)&sB[(wc*64 + nf*16 + l15)*LDT + ks*32 + l4*8];
      #pragma unroll
      for (int mf = 0; mf < 4; ++mf)
        #pragma unroll
        for (int nf = 0; nf < 4; ++nf)
          acc[mf][nf] = __builtin_amdgcn_mfma_f32_16x16x32_bf16(
              af[mf], bb[nf], acc[mf][nf], 0, 0, 0);
    }
    __syncthreads();
  }
  #pragma unroll
  for (int mf = 0; mf < 4; ++mf)
    #pragma unroll
    for (int nf = 0; nf < 4; ++nf)
      #pragma unroll
      for (int r = 0; r < 4; ++r) {
        int row = m0 + wr*64 + mf*16 + l4*4 + r;
        int col = n0 + wc*64 + nf*16 + l15;
        float v = acc[mf][nf][r];
        if (col < 256) out[(size_t)row*D_ + col] = v;
        else           out[PLANE + (size_t)row*D_ + col - 256] = v;
      }
}

// ---------------------------------------------------------------------------
// Scan with fused coefficient computation. One block per (b,n); thread = d.
// ---------------------------------------------------------------------------
__global__ __launch_bounds__(256) void scan_kernel(
  const float* __restrict__ eps, const float* __restrict__ dt,
  const float* __restrict__ lam_re, const float* __restrict__ lam_im,
  const float* __restrict__ noise_raw,
  const u16* __restrict__ xer16, const u16* __restrict__ xei16,
  u16* __restrict__ hre16, u16* __restrict__ him16)
{
  int bx = blockIdx.x;
  int b = bx >> 9, n = bx & 511;
  int d = threadIdx.x;
  __shared__ float sdt[T_];
  if (d < T_) sdt[d] = dt[b*T_ + d];
  __syncthreads();

  float lr = lam_re[d], li = lam_im[d];
  float lam_r = fmaxf(-log1pf(expf(-lr)), -0.3f);     // -softplus(-x), clamp
  float t0 = lam_r + 1e-12f;
  float sgn = (t0 > 0.f) ? 1.f : ((t0 < 0.f) ? -1.f : 0.f);
  float den_re = lam_r + 1e-8f*sgn, den_im = li;      // lam_safe
  float d2 = den_re*den_re + den_im*den_im;
  float nsc = log1pf(expf(noise_raw[d])) * 0.01f;

  float hr = 0.f, hi = 0.f;
  for (int t = 0; t < T_; ++t) {
    float dtv = sdt[t];
    float er = expf(dtv*lam_r);
    float ai = dtv*li;
    float dre = er*cosf(ai), dim_ = er*sinf(ai);
    float nr = dre - 1.f, ni = dim_;
    float fre = (nr*den_re + ni*den_im)/d2;
    float fim = (ni*den_re - nr*den_im)/d2;
    float ns = sqrtf(fmaxf(dtv, 0.f)) * nsc;
    size_t idx = ((size_t)(b*T_ + t)*N_ + n)*D_ + d;
    float xr = bf2f(xer16[idx]), xi = bf2f(xei16[idx]), ep = eps[idx];
    float br = fre*xr - fim*xi + ep*ns;
    float bi = fre*xi + fim*xr;
    float nr2 = dre*hr - dim_*hi + br;
    float ni2 = dre*hi + dim_*hr + bi;
    hr = nr2; hi = ni2;
    hre16[idx] = f2bf(hr); him16[idx] = f2bf(hi);
  }
}

// ---------------------------------------------------------------------------
extern "C" void kernel_launch(void* const* d_in, const int* in_sizes, int n_in,
                              void* d_out, int out_size, void* d_ws, size_t ws_size,
                              hipStream_t stream)
{
  const float* x         = (const float*)d_in[0];
  const float* dt        = (const float*)d_in[1];
  const float* eps       = (const float*)d_in[2];
  const float* ure_raw   = (const float*)d_in[3];
  const float* uim_raw   = (const float*)d_in[4];
  const float* lam_re    = (const float*)d_in[5];
  const float* lam_im    = (const float*)d_in[6];
  const float* noise_raw = (const float*)d_in[7];
  float* out = (float*)d_out;

  // ws layout (132 MB total):
  //   0       A float2[65536]            512 KB
  //   512K    tau float2[256]            2 KB
  //   1M      Benc bf16 [512][256]       256 KB
  //   1.5M    Bdec bf16 [512][512]       512 KB
  //   4M      hre16 bf16 [M][256] 32 MB
  //   36M     xer16 32 MB
  //   68M     xei16 32 MB
  //   100M    him16 32 MB
  char* ws = (char*)d_ws;
  float2* A    = (float2*)(ws);
  float2* tau  = (float2*)(ws + 524288);
  u16* Benc    = (u16*)(ws + (1<<20));
  u16* Bdec    = (u16*)(ws + 1572864);
  u16* hre16   = (u16*)(ws + ((size_t)4<<20));
  u16* xer16   = (u16*)(ws + ((size_t)36<<20));
  u16* xei16   = (u16*)(ws + ((size_t)68<<20));
  u16* him16   = (u16*)(ws + ((size_t)100<<20));

  qr_megastep<0><<<8, 1024, 0, stream>>>(ure_raw, uim_raw, A, tau);
  qr_megastep<1><<<7, 1024, 0, stream>>>(ure_raw, uim_raw, A, tau);
  qr_megastep<2><<<6, 1024, 0, stream>>>(ure_raw, uim_raw, A, tau);
  qr_megastep<3><<<5, 1024, 0, stream>>>(ure_raw, uim_raw, A, tau);
  qr_megastep<4><<<4, 1024, 0, stream>>>(ure_raw, uim_raw, A, tau);
  qr_megastep<5><<<3, 1024, 0, stream>>>(ure_raw, uim_raw, A, tau);
  qr_megastep<6><<<2, 1024, 0, stream>>>(ure_raw, uim_raw, A, tau);
  qr_megastep<7><<<1, 1024, 0, stream>>>(ure_raw, uim_raw, A, tau);
  qr_bwd_kernel<<<64, 256, 0, stream>>>(A, tau, Benc, Bdec);
  encode_gemm<<<dim3(M_/128, 4), 256, 0, stream>>>(x, Benc, xer16, xei16);
  scan_kernel<<<B_*N_, 256, 0, stream>>>(eps, dt, lam_re, lam_im, noise_raw,
                                         xer16, xei16, hre16, him16);
  decode_gemm<<<dim3(M_/128, 4), 256, 0, stream>>>(hre16, him16, Bdec, out);
}

// Round 15
// 737.173 us; speedup vs baseline: 1.7792x; 1.0168x over previous
//
#include <hip/hip_runtime.h>
#include <math.h>

// Problem constants (B,T,N,D) = (2,64,512,256)
#define B_ 2
#define T_ 64
#define N_ 512
#define D_ 256
#define M_ (B_*T_*N_)            // 65536 rows for the GEMMs
#define PLANE ((size_t)M_*D_)    // 16777216 elements per output plane

typedef unsigned short u16;
typedef __attribute__((ext_vector_type(8))) short bf16x8;
typedef __attribute__((ext_vector_type(4))) float f32x4;

__device__ __forceinline__ u16 f2bf(float f) {
  union { float f; unsigned u; } cv; cv.f = f;
  unsigned u = cv.u;
  return (u16)((u + 0x7FFFu + ((u >> 16) & 1u)) >> 16);   // RNE
}
__device__ __forceinline__ float bf2f(u16 h) {
  union { unsigned u; float f; } cv; cv.u = ((unsigned)h) << 16;
  return cv.f;
}

// 64-lane sum via DPP (VALU-only). Result wave-uniform via readlane 63.
__device__ __forceinline__ float wredsum(float x) {
  x += __uint_as_float(__builtin_amdgcn_update_dpp(0u, __float_as_uint(x), 0x111, 0xf, 0xf, true));
  x += __uint_as_float(__builtin_amdgcn_update_dpp(0u, __float_as_uint(x), 0x112, 0xf, 0xf, true));
  x += __uint_as_float(__builtin_amdgcn_update_dpp(0u, __float_as_uint(x), 0x114, 0xf, 0xf, true));
  x += __uint_as_float(__builtin_amdgcn_update_dpp(0u, __float_as_uint(x), 0x118, 0xf, 0xf, true));
  x += __uint_as_float(__builtin_amdgcn_update_dpp(0u, __float_as_uint(x), 0x142, 0xa, 0xf, true));
  x += __uint_as_float(__builtin_amdgcn_update_dpp(0u, __float_as_uint(x), 0x143, 0xc, 0xf, true));
  return __uint_as_float(__builtin_amdgcn_readlane(__float_as_uint(x), 63));
}
__device__ __forceinline__ float lanebcast(float x, int l) {
  return __uint_as_float(__builtin_amdgcn_readlane(__float_as_uint(x), l));
}

// ---------------------------------------------------------------------------
// Megastep P (r14 owner-precompute factorize; measured <86us each).
// 1024 threads = 16 waves; wave w owns cols {2w, 2w+1}.
// ---------------------------------------------------------------------------
template<int P>
__global__ __launch_bounds__(1024, 1) void qr_megastep(
    const float* __restrict__ ure_raw, const float* __restrict__ uim_raw,
    float2* __restrict__ A, float2* __restrict__ tau)
{
  const int tid = threadIdx.x, lane = tid & 63, w = tid >> 6;   // w 0..15
  const int role = blockIdx.x;
  __shared__ float2 sv32[32][256];
  __shared__ float2 sfin[32][256];
  __shared__ float2 snext[2][256];
  __shared__ float2 stau2[2];
  __shared__ float2 stau32[32];
  __shared__ float2 stauOut[32];

  constexpr int J0P  = (P > 0) ? 32*(P-1) : 0;   // prev-panel start
  constexpr int RP   = 256 - J0P;
  constexpr int MCHP = (RP + 63) >> 6;
  constexpr int PIV  = (P == 0) ? 0 : 32;        // pivot row offset in window
  constexpr int J0W  = (P == 0) ? 0 : J0P;       // factorize window start
  constexpr int RW   = 256 - J0W;
  constexpr int MCHW = (RW + 63) >> 6;

  if constexpr (P == 0) {
    if (role > 0) {
      const int c0 = 32*role;
      const int c = tid & 31, r0 = tid >> 5;     // r0 0..31
      #pragma unroll
      for (int r8 = 0; r8 < 8; ++r8) {
        int r = r0 + r8*32;
        A[(size_t)(c0+c)*D_ + r] = make_float2(ure_raw[(size_t)r*D_ + c0 + c],
                                               uim_raw[(size_t)r*D_ + c0 + c]);
      }
      return;
    }
  }

  float2 col[2][4];

  if constexpr (P > 0) {
    // ---- stage V_{P-1} and taus; load own cols ----
    #pragma unroll
    for (int it = 0; it < 8; ++it) {
      int idx = it*1024 + tid;
      int c = idx >> 8, rr = idx & 255;
      float2 val = make_float2(0.f, 0.f);
      if (rr < RP) val = A[(size_t)(J0P+c)*D_ + J0P + rr];
      sv32[c][rr] = val;
    }
    if (tid < 32) stau32[tid] = tau[J0P + tid];
    const int c0 = (role > 0) ? 32*(P + role) : 32*P;
    #pragma unroll
    for (int lc = 0; lc < 2; ++lc) {
      int cg = c0 + 2*w + lc;
      #pragma unroll
      for (int m = 0; m < 4; ++m) {
        int rr = m*64 + lane;
        col[lc][m] = make_float2(0.f, 0.f);
        if (m < MCHP && rr < RP) col[lc][m] = A[(size_t)cg*D_ + J0P + rr];
      }
    }
    __syncthreads();

    // ---- fused reflector apply: 32 dependent steps, 2 cols/wave ----
    #pragma unroll 4
    for (int jl = 0; jl < 32; ++jl) {
      float2 tt = stau32[jl];
      float2 v[4];
      { float2 rv = sv32[jl][lane];
        v[0] = (lane > jl) ? rv : ((lane == jl) ? make_float2(1.f, 0.f)
                                                : make_float2(0.f, 0.f)); }
      #pragma unroll
      for (int m = 1; m < 4; ++m) v[m] = sv32[jl][m*64 + lane];
      float wr[2], wi[2];
      #pragma unroll
      for (int lc = 0; lc < 2; ++lc) {
        wr[lc] = 0.f; wi[lc] = 0.f;
        #pragma unroll
        for (int m = 0; m < 4; ++m) {
          if (m < MCHP) {
            float2 a = col[lc][m];
            wr[lc] += v[m].x*a.x + v[m].y*a.y;   // conj(v)*a
            wi[lc] += v[m].x*a.y - v[m].y*a.x;
          }
        }
      }
      #pragma unroll
      for (int lc = 0; lc < 2; ++lc) { wr[lc] = wredsum(wr[lc]);
                                       wi[lc] = wredsum(wi[lc]); }
      #pragma unroll
      for (int lc = 0; lc < 2; ++lc) {
        float fr = tt.x*wr[lc] + tt.y*wi[lc];    // f = conj(tau)*w
        float fi = tt.x*wi[lc] - tt.y*wr[lc];
        #pragma unroll
        for (int m = 0; m < 4; ++m) {
          if (m < MCHP) {
            col[lc][m].x -= fr*v[m].x - fi*v[m].y;
            col[lc][m].y -= fr*v[m].y + fi*v[m].x;
          }
        }
      }
    }

    if (role > 0) {
      #pragma unroll
      for (int lc = 0; lc < 2; ++lc) {
        int cg = 32*(P + role) + 2*w + lc;
        #pragma unroll
        for (int m = 0; m < 4; ++m) {
          int rr = m*64 + lane;
          if (m < MCHP && rr < RP) A[(size_t)cg*D_ + J0P + rr] = col[lc][m];
        }
      }
      return;
    }
    __syncthreads();
  } else {
    // P == 0, role 0: init panel 0 into registers (transposed raw read)
    #pragma unroll
    for (int lc = 0; lc < 2; ++lc) {
      int cg = 2*w + lc;
      #pragma unroll
      for (int m = 0; m < 4; ++m) {
        int rr = m*64 + lane;
        col[lc][m] = make_float2(ure_raw[(size_t)rr*D_ + cg],
                                 uim_raw[(size_t)rr*D_ + cg]);
      }
    }
  }

  // ===== role 0: factorize panel P, owner-precompute pipeline =====
  if (w == 0) {
    float part = (lane > PIV) ? (col[0][0].x*col[0][0].x + col[0][0].y*col[0][0].y) : 0.f;
    if (1 < MCHW) part += col[0][1].x*col[0][1].x + col[0][1].y*col[0][1].y;
    if (2 < MCHW) part += col[0][2].x*col[0][2].x + col[0][2].y*col[0][2].y;
    if (3 < MCHW) part += col[0][3].x*col[0][3].x + col[0][3].y*col[0][3].y;
    part = wredsum(part);
    float ar = lanebcast(col[0][0].x, PIV), ai = lanebcast(col[0][0].y, PIV);
    float tr, ti, sr, si, bt;
    if (part == 0.f && ai == 0.f) {
      tr = ti = sr = si = 0.f; bt = ar;                // H = I
    } else {
      float nrm = sqrtf(ar*ar + ai*ai + part);
      bt = (ar >= 0.f) ? -nrm : nrm;                   // -SIGN(nrm, Re(alpha))
      tr = (bt - ar)/bt; ti = -ai/bt;
      float dr = ar - bt, di = ai, dn = dr*dr + di*di;
      sr = dr/dn; si = -di/dn;                         // 1/(alpha-beta)
    }
    if (lane == 0) { stau2[0] = make_float2(tr, ti);
                     stauOut[0] = make_float2(tr, ti); }
    float2 nv0 = make_float2(col[0][0].x*sr - col[0][0].y*si,
                             col[0][0].x*si + col[0][0].y*sr);
    nv0 = (lane > PIV) ? nv0 : ((lane == PIV) ? make_float2(1.f, 0.f)
                                              : make_float2(0.f, 0.f));
    float2 nv1 = make_float2(col[0][1].x*sr - col[0][1].y*si,
                             col[0][1].x*si + col[0][1].y*sr);
    float2 nv2 = make_float2(col[0][2].x*sr - col[0][2].y*si,
                             col[0][2].x*si + col[0][2].y*sr);
    float2 nv3 = make_float2(col[0][3].x*sr - col[0][3].y*si,
                             col[0][3].x*si + col[0][3].y*sr);
    snext[0][lane]       = nv0;
    snext[0][64 + lane]  = nv1;
    snext[0][128 + lane] = nv2;
    snext[0][192 + lane] = nv3;
    float2 o0 = (lane < PIV) ? col[0][0]
              : ((lane == PIV) ? make_float2(bt, 0.f) : nv0);
    sfin[0][lane] = o0;
    if (1 < MCHW) sfin[0][64 + lane]  = nv1;
    if (2 < MCHW) sfin[0][128 + lane] = nv2;
    if (3 < MCHW) sfin[0][192 + lane] = nv3;
  }
  __syncthreads();

  #pragma unroll 1
  for (int jl = 0; jl < 31; ++jl) {            // step 31 would update nothing
    const int cur = jl & 1, nxt = cur ^ 1;
    float2 v0 = snext[cur][lane],      v1 = snext[cur][64 + lane],
           v2 = snext[cur][128 + lane], v3 = snext[cur][192 + lane];
    float2 tt = stau2[cur];                    // LDS broadcast
    #pragma unroll
    for (int lc = 0; lc < 2; ++lc) {
      int cl = 2*w + lc;
      if (cl > jl) {
        float wr, wi;
        { float2 a = col[lc][0];
          wr = v0.x*a.x + v0.y*a.y; wi = v0.x*a.y - v0.y*a.x; }
        if (1 < MCHW) { float2 a = col[lc][1];
          wr += v1.x*a.x + v1.y*a.y; wi += v1.x*a.y - v1.y*a.x; }
        if (2 < MCHW) { float2 a = col[lc][2];
          wr += v2.x*a.x + v2.y*a.y; wi += v2.x*a.y - v2.y*a.x; }
        if (3 < MCHW) { float2 a = col[lc][3];
          wr += v3.x*a.x + v3.y*a.y; wi += v3.x*a.y - v3.y*a.x; }
        wr = wredsum(wr); wi = wredsum(wi);
        float fr = tt.x*wr + tt.y*wi;          // f = conj(tau)*w
        float fi = tt.x*wi - tt.y*wr;
        { col[lc][0].x -= fr*v0.x - fi*v0.y;
          col[lc][0].y -= fr*v0.y + fi*v0.x; }
        if (1 < MCHW) { col[lc][1].x -= fr*v1.x - fi*v1.y;
                        col[lc][1].y -= fr*v1.y + fi*v1.x; }
        if (2 < MCHW) { col[lc][2].x -= fr*v2.x - fi*v2.y;
                        col[lc][2].y -= fr*v2.y + fi*v2.x; }
        if (3 < MCHW) { col[lc][3].x -= fr*v3.x - fi*v3.y;
                        col[lc][3].y -= fr*v3.y + fi*v3.x; }
        if (cl == jl + 1) {
          // owner: produce reflector jl+1 from the just-updated column
          const int pr = PIV + jl + 1;         // pivot row, always chunk 0
          float part = (lane > pr) ? (col[lc][0].x*col[lc][0].x +
                                      col[lc][0].y*col[lc][0].y) : 0.f;
          if (1 < MCHW) part += col[lc][1].x*col[lc][1].x + col[lc][1].y*col[lc][1].y;
          if (2 < MCHW) part += col[lc][2].x*col[lc][2].x + col[lc][2].y*col[lc][2].y;
          if (3 < MCHW) part += col[lc][3].x*col[lc][3].x + col[lc][3].y*col[lc][3].y;
          part = wredsum(part);
          float ar = lanebcast(col[lc][0].x, pr), ai = lanebcast(col[lc][0].y, pr);
          float tr, ti, sr, si, bt;
          if (part == 0.f && ai == 0.f) {
            tr = ti = sr = si = 0.f; bt = ar;          // H = I
          } else {
            float nrm = sqrtf(ar*ar + ai*ai + part);
            bt = (ar >= 0.f) ? -nrm : nrm;             // -SIGN(nrm, Re(alpha))
            tr = (bt - ar)/bt; ti = -ai/bt;
            float dr = ar - bt, di = ai, dn = dr*dr + di*di;
            sr = dr/dn; si = -di/dn;                   // 1/(alpha-beta)
          }
          if (lane == 0) { stau2[nxt] = make_float2(tr, ti);
                           stauOut[jl+1] = make_float2(tr, ti); }
          float2 m0v = make_float2(col[lc][0].x*sr - col[lc][0].y*si,
                                   col[lc][0].x*si + col[lc][0].y*sr);
          m0v = (lane > pr) ? m0v : ((lane == pr) ? make_float2(1.f, 0.f)
                                                  : make_float2(0.f, 0.f));
          float2 m1v = make_float2(col[lc][1].x*sr - col[lc][1].y*si,
                                   col[lc][1].x*si + col[lc][1].y*sr);
          float2 m2v = make_float2(col[lc][2].x*sr - col[lc][2].y*si,
                                   col[lc][2].x*si + col[lc][2].y*sr);
          float2 m3v = make_float2(col[lc][3].x*sr - col[lc][3].y*si,
                                   col[lc][3].x*si + col[lc][3].y*sr);
          snext[nxt][lane]       = m0v;
          snext[nxt][64 + lane]  = m1v;
          snext[nxt][128 + lane] = m2v;
          snext[nxt][192 + lane] = m3v;
          float2 o0 = (lane < pr) ? col[lc][0]
                    : ((lane == pr) ? make_float2(bt, 0.f) : m0v);
          sfin[jl+1][lane] = o0;
          if (1 < MCHW) sfin[jl+1][64 + lane]  = m1v;
          if (2 < MCHW) sfin[jl+1][128 + lane] = m2v;
          if (3 < MCHW) sfin[jl+1][192 + lane] = m3v;
        }
      }
    }
    __syncthreads();
  }

  // ---- batch-write panel columns + taus to global ----
  #pragma unroll
  for (int it = 0; it < 8; ++it) {
    int idx = it*1024 + tid;
    int c = idx >> 8, rr = idx & 255;
    if (rr < RW) A[(size_t)(32*P + c)*D_ + J0W + rr] = sfin[c][rr];
  }
  if (tid < 32) tau[32*P + tid] = stauOut[tid];
}

// ---------------------------------------------------------------------------
// zung2r: column c of Q = H_0(...H_c(e_c)); one wave per column; depth-2
// register prefetch; DPP reduce. Epilogue writes bf16 B^T matrices.
// ---------------------------------------------------------------------------
__global__ __launch_bounds__(256, 1) void qr_bwd_kernel(
    const float2* __restrict__ A, const float2* __restrict__ tau,
    u16* __restrict__ Benc, u16* __restrict__ Bdec)
{
  const int lane = threadIdx.x & 63;
  const int w = threadIdx.x >> 6;
  const int c = blockIdx.x * 4 + w;          // column 0..255
  __shared__ float2 stau[256];
  if (threadIdx.x < 256) stau[threadIdx.x] = tau[threadIdx.x];
  __syncthreads();

  float2 q[4];
  #pragma unroll
  for (int m = 0; m < 4; ++m) {
    q[m] = make_float2(0.f, 0.f);
    if (m*64 + lane == c) q[m].x = 1.f;      // q = e_c
  }
  float2 a0[4], a1[4];
  #pragma unroll
  for (int m = 0; m < 4; ++m) a0[m] = A[(size_t)c*D_ + m*64 + lane];
  {
    int i1 = (c >= 1) ? c - 1 : 0;
    #pragma unroll
    for (int m = 0; m < 4; ++m) a1[m] = A[(size_t)i1*D_ + m*64 + lane];
  }

  #pragma unroll 1
  for (int i = c; i >= 0; --i) {
    int ip = (i >= 2) ? i - 2 : 0;
    float2 a2[4];
    #pragma unroll
    for (int m = 0; m < 4; ++m) a2[m] = A[(size_t)ip*D_ + m*64 + lane];

    float2 tt = stau[i];
    float2 v[4];
    #pragma unroll
    for (int m = 0; m < 4; ++m) {
      int r = m*64 + lane;
      v[m] = (r > i) ? a0[m] : ((r == i) ? make_float2(1.f, 0.f)
                                         : make_float2(0.f, 0.f));
    }
    float wr = 0.f, wi = 0.f;
    #pragma unroll
    for (int m = 0; m < 4; ++m) {
      wr += v[m].x*q[m].x + v[m].y*q[m].y;   // w += conj(v)*q
      wi += v[m].x*q[m].y - v[m].y*q[m].x;
    }
    wr = wredsum(wr); wi = wredsum(wi);
    float fr = tt.x*wr - tt.y*wi;            // f = tau*w (0 when tau==0)
    float fi = tt.x*wi + tt.y*wr;
    #pragma unroll
    for (int m = 0; m < 4; ++m) {
      q[m].x -= fr*v[m].x - fi*v[m].y;
      q[m].y -= fr*v[m].y + fi*v[m].x;
      a0[m] = a1[m]; a1[m] = a2[m];
    }
  }

  #pragma unroll
  for (int m = 0; m < 4; ++m) {
    int r = m*64 + lane;
    u16 qre = f2bf(q[m].x), qim = f2bf(q[m].y), qimn = f2bf(-q[m].y);
    Benc[(size_t)c*D_ + r]              = qre;
    Benc[(size_t)(c+256)*D_ + r]        = qim;
    Bdec[(size_t)c*512 + r]             = qre;
    Bdec[(size_t)c*512 + 256 + r]       = qimn;
    Bdec[(size_t)(c+256)*512 + r]       = qim;
    Bdec[(size_t)(c+256)*512 + 256 + r] = qre;
  }
}

// ---------------------------------------------------------------------------
// Per-(b,t,d) coefficient tables (r14 post-mortem: fusing these into scan
// made scan VALU-bound at 73% VALUBusy / 19% HBM — 50M transcendental
// sequences. Tables are 640 KB, L2-resident; scan returns to memory-bound).
// ---------------------------------------------------------------------------
__global__ __launch_bounds__(256) void coef_kernel(
  const float* __restrict__ dt, const float* __restrict__ lam_re, const float* __restrict__ lam_im,
  const float* __restrict__ noise_raw,
  float* __restrict__ c_dre, float* __restrict__ c_dim, float* __restrict__ c_fre,
  float* __restrict__ c_fim, float* __restrict__ c_ns)
{
  int bt = blockIdx.x; int d = threadIdx.x;
  float dtv = dt[bt];
  float lr = lam_re[d], li = lam_im[d];
  float lam_r = fmaxf(-log1pf(expf(-lr)), -0.3f);     // -softplus(-x), clamp
  float ar = dtv*lam_r, ai = dtv*li;
  float er = expf(ar);
  float dre = er*cosf(ai), dim_ = er*sinf(ai);
  float t = lam_r + 1e-12f;
  float sgn = (t > 0.f) ? 1.f : ((t < 0.f) ? -1.f : 0.f);
  float den_re = lam_r + 1e-8f*sgn, den_im = li;      // lam_safe
  float nr = dre - 1.f, ni = dim_;
  float d2 = den_re*den_re + den_im*den_im;
  float fre = (nr*den_re + ni*den_im)/d2;
  float fim = (ni*den_re - nr*den_im)/d2;
  float ns = sqrtf(fmaxf(dtv,0.f)) * log1pf(expf(noise_raw[d])) * 0.01f;
  int idx = bt*D_+d;
  c_dre[idx]=dre; c_dim[idx]=dim_; c_fre[idx]=fre; c_fim[idx]=fim; c_ns[idx]=ns;
}

// ---------------------------------------------------------------------------
// bf16 MFMA GEMM, 128x128 tile, 4 waves, BK=64, 16x16x32 MFMA.
// encode_gemm reads fp32 x directly and converts during staging.
// ---------------------------------------------------------------------------
#define LDT 72

__global__ __launch_bounds__(256) void encode_gemm(
    const float* __restrict__ x, const u16* __restrict__ Bt,
    u16* __restrict__ xer16, u16* __restrict__ xei16)
{
  __shared__ u16 sA[128*LDT];
  __shared__ u16 sB[128*LDT];
  const int tid = threadIdx.x;
  const int lane = tid & 63, w = tid >> 6;
  const int wr = w >> 1, wc = w & 1;
  const int l15 = lane & 15, l4 = lane >> 4;
  const int m0 = blockIdx.x * 128;
  const int n0 = blockIdx.y * 128;
  f32x4 acc[4][4] = {};
  for (int kb = 0; kb < 4; ++kb) {
    #pragma unroll
    for (int i = 0; i < 4; ++i) {
      int chunk = i*256 + tid;
      int row = chunk >> 3, k0 = (chunk & 7) * 8;
      const float* xs = x + (size_t)(m0+row)*D_ + kb*64 + k0;
      float4 f0 = *(const float4*)xs;
      float4 f1 = *(const float4*)(xs + 4);
      int4 va;
      va.x = (int)((unsigned)f2bf(f0.x) | ((unsigned)f2bf(f0.y) << 16));
      va.y = (int)((unsigned)f2bf(f0.z) | ((unsigned)f2bf(f0.w) << 16));
      va.z = (int)((unsigned)f2bf(f1.x) | ((unsigned)f2bf(f1.y) << 16));
      va.w = (int)((unsigned)f2bf(f1.z) | ((unsigned)f2bf(f1.w) << 16));
      int4 vb = *(const int4*)(Bt + (size_t)(n0+row)*D_ + kb*64 + k0);
      *(int4*)&sA[row*LDT + k0] = va;
      *(int4*)&sB[row*LDT + k0] = vb;
    }
    __syncthreads();
    #pragma unroll
    for (int ks = 0; ks < 2; ++ks) {
      bf16x8 af[4], bb[4];
      #pragma unroll
      for (int mf = 0; mf < 4; ++mf)
        af[mf] = *(const bf16x8*)&sA[(wr*64 + mf*16 + l15)*LDT + ks*32 + l4*8];
      #pragma unroll
      for (int nf = 0; nf < 4; ++nf)
        bb[nf] = *(const bf16x8*)&sB[(wc*64 + nf*16 + l15)*LDT + ks*32 + l4*8];
      #pragma unroll
      for (int mf = 0; mf < 4; ++mf)
        #pragma unroll
        for (int nf = 0; nf < 4; ++nf)
          acc[mf][nf] = __builtin_amdgcn_mfma_f32_16x16x32_bf16(
              af[mf], bb[nf], acc[mf][nf], 0, 0, 0);
    }
    __syncthreads();
  }
  #pragma unroll
  for (int mf = 0; mf < 4; ++mf)
    #pragma unroll
    for (int nf = 0; nf < 4; ++nf)
      #pragma unroll
      for (int r = 0; r < 4; ++r) {
        int row = m0 + wr*64 + mf*16 + l4*4 + r;
        int col = n0 + wc*64 + nf*16 + l15;
        float v = acc[mf][nf][r];
        if (col < 256) xer16[(size_t)row*D_ + col] = f2bf(v);
        else           xei16[(size_t)row*D_ + col - 256] = f2bf(-v);
      }
}

__global__ __launch_bounds__(256) void decode_gemm(
    const u16* __restrict__ hre16, const u16* __restrict__ him16,
    const u16* __restrict__ Bt, float* __restrict__ out)
{
  __shared__ u16 sA[128*LDT];
  __shared__ u16 sB[128*LDT];
  const int tid = threadIdx.x;
  const int lane = tid & 63, w = tid >> 6;
  const int wr = w >> 1, wc = w & 1;
  const int l15 = lane & 15, l4 = lane >> 4;
  const int m0 = blockIdx.x * 128;
  const int n0 = blockIdx.y * 128;
  f32x4 acc[4][4] = {};
  for (int kb = 0; kb < 8; ++kb) {
    const u16* aplane = (kb < 4) ? hre16 : him16;
    const int kk = (kb & 3) * 64;
    #pragma unroll
    for (int i = 0; i < 4; ++i) {
      int chunk = i*256 + tid;
      int row = chunk >> 3, k0 = (chunk & 7) * 8;
      int4 va = *(const int4*)(aplane + (size_t)(m0+row)*D_ + kk + k0);
      int4 vb = *(const int4*)(Bt + (size_t)(n0+row)*512 + kb*64 + k0);
      *(int4*)&sA[row*LDT + k0] = va;
      *(int4*)&sB[row*LDT + k0] = vb;
    }
    __syncthreads();
    #pragma unroll
    for (int ks = 0; ks < 2; ++ks) {
      bf16x8 af[4], bb[4];
      #pragma unroll
      for (int mf = 0; mf < 4; ++mf)
        af[mf] = *(const bf16x8*)&sA[(wr*64 + mf*16 + l15)*LDT + ks*32 + l4*8];
      #pragma unroll
      for (int nf = 0; nf < 4; ++nf)
        bb[nf] = *(const bf16x8*)&sB[(wc*64 + nf*16 + l15)*LDT + ks*32 + l4*8];
      #pragma unroll
      for (int mf = 0; mf < 4; ++mf)
        #pragma unroll
        for (int nf = 0; nf < 4; ++nf)
          acc[mf][nf] = __builtin_amdgcn_mfma_f32_16x16x32_bf16(
              af[mf], bb[nf], acc[mf][nf], 0, 0, 0);
    }
    __syncthreads();
  }
  #pragma unroll
  for (int mf = 0; mf < 4; ++mf)
    #pragma unroll
    for (int nf = 0; nf < 4; ++nf)
      #pragma unroll
      for (int r = 0; r < 4; ++r) {
        int row = m0 + wr*64 + mf*16 + l4*4 + r;
        int col = n0 + wc*64 + nf*16 + l15;
        float v = acc[mf][nf][r];
        if (col < 256) out[(size_t)row*D_ + col] = v;
        else           out[PLANE + (size_t)row*D_ + col - 256] = v;
      }
}

// ---------------------------------------------------------------------------
// Scan: reads bf16 x_enc planes + fp32 eps + coef tables (L2-resident);
// writes bf16 h planes. One block per (b,n); thread = d. Memory-bound.
// ---------------------------------------------------------------------------
__global__ __launch_bounds__(256) void scan_kernel(
  const float* __restrict__ eps,
  const float* __restrict__ c_dre, const float* __restrict__ c_dim,
  const float* __restrict__ c_fre, const float* __restrict__ c_fim, const float* __restrict__ c_ns,
  const u16* __restrict__ xer16, const u16* __restrict__ xei16,
  u16* __restrict__ hre16, u16* __restrict__ him16)
{
  int bx = blockIdx.x;
  int b = bx >> 9, n = bx & 511;
  int d = threadIdx.x;
  float hr = 0.f, hi = 0.f;
  for (int t = 0; t < T_; ++t) {
    int bt = b*T_ + t;
    int cidx = bt*D_ + d;
    float dre = c_dre[cidx], dim_ = c_dim[cidx];
    float fre = c_fre[cidx], fim = c_fim[cidx];
    float ns  = c_ns[cidx];
    size_t idx = ((size_t)bt*N_ + n)*D_ + d;
    float xr = bf2f(xer16[idx]), xi = bf2f(xei16[idx]), ep = eps[idx];
    float br = fre*xr - fim*xi + ep*ns;
    float bi = fre*xi + fim*xr;
    float nr2 = dre*hr - dim_*hi + br;
    float ni2 = dre*hi + dim_*hr + bi;
    hr = nr2; hi = ni2;
    hre16[idx] = f2bf(hr); him16[idx] = f2bf(hi);
  }
}

// ---------------------------------------------------------------------------
extern "C" void kernel_launch(void* const* d_in, const int* in_sizes, int n_in,
                              void* d_out, int out_size, void* d_ws, size_t ws_size,
                              hipStream_t stream)
{
  const float* x         = (const float*)d_in[0];
  const float* dt        = (const float*)d_in[1];
  const float* eps       = (const float*)d_in[2];
  const float* ure_raw   = (const float*)d_in[3];
  const float* uim_raw   = (const float*)d_in[4];
  const float* lam_re    = (const float*)d_in[5];
  const float* lam_im    = (const float*)d_in[6];
  const float* noise_raw = (const float*)d_in[7];
  float* out = (float*)d_out;

  // ws layout (132 MB total):
  //   0       A float2[65536]            512 KB
  //   512K    tau float2[256]            2 KB
  //   1M      Benc bf16 [512][256]       256 KB
  //   1.5M    Bdec bf16 [512][512]       512 KB
  //   2M      coef tables 5 x 128 KB     640 KB
  //   4M      hre16 bf16 [M][256] 32 MB
  //   36M     xer16 32 MB
  //   68M     xei16 32 MB
  //   100M    him16 32 MB
  char* ws = (char*)d_ws;
  float2* A    = (float2*)(ws);
  float2* tau  = (float2*)(ws + 524288);
  u16* Benc    = (u16*)(ws + (1<<20));
  u16* Bdec    = (u16*)(ws + 1572864);
  float* c_dre = (float*)(ws + (2<<20));
  float* c_dim = c_dre + B_*T_*D_;
  float* c_fre = c_dim + B_*T_*D_;
  float* c_fim = c_fre + B_*T_*D_;
  float* c_ns  = c_fim + B_*T_*D_;
  u16* hre16   = (u16*)(ws + ((size_t)4<<20));
  u16* xer16   = (u16*)(ws + ((size_t)36<<20));
  u16* xei16   = (u16*)(ws + ((size_t)68<<20));
  u16* him16   = (u16*)(ws + ((size_t)100<<20));

  qr_megastep<0><<<8, 1024, 0, stream>>>(ure_raw, uim_raw, A, tau);
  qr_megastep<1><<<7, 1024, 0, stream>>>(ure_raw, uim_raw, A, tau);
  qr_megastep<2><<<6, 1024, 0, stream>>>(ure_raw, uim_raw, A, tau);
  qr_megastep<3><<<5, 1024, 0, stream>>>(ure_raw, uim_raw, A, tau);
  qr_megastep<4><<<4, 1024, 0, stream>>>(ure_raw, uim_raw, A, tau);
  qr_megastep<5><<<3, 1024, 0, stream>>>(ure_raw, uim_raw, A, tau);
  qr_megastep<6><<<2, 1024, 0, stream>>>(ure_raw, uim_raw, A, tau);
  qr_megastep<7><<<1, 1024, 0, stream>>>(ure_raw, uim_raw, A, tau);
  qr_bwd_kernel<<<64, 256, 0, stream>>>(A, tau, Benc, Bdec);
  coef_kernel<<<B_*T_, 256, 0, stream>>>(dt, lam_re, lam_im, noise_raw,
                                         c_dre, c_dim, c_fre, c_fim, c_ns);
  encode_gemm<<<dim3(M_/128, 4), 256, 0, stream>>>(x, Benc, xer16, xei16);
  scan_kernel<<<B_*N_, 256, 0, stream>>>(eps, c_dre, c_dim, c_fre, c_fim, c_ns,
                                         xer16, xei16, hre16, him16);
  decode_gemm<<<dim3(M_/128, 4), 256, 0, stream>>>(hre16, him16, Bdec, out);
}

// Round 16
// 730.890 us; speedup vs baseline: 1.7944x; 1.0086x over previous
//
#include <hip/hip_runtime.h>
#include <math.h>

// Problem constants (B,T,N,D) = (2,64,512,256)
#define B_ 2
#define T_ 64
#define N_ 512
#define D_ 256
#define M_ (B_*T_*N_)            // 65536 rows for the GEMMs
#define PLANE ((size_t)M_*D_)    // 16777216 elements per output plane

typedef unsigned short u16;
typedef __attribute__((ext_vector_type(8))) short bf16x8;
typedef __attribute__((ext_vector_type(4))) float f32x4;

__device__ __forceinline__ u16 f2bf(float f) {
  union { float f; unsigned u; } cv; cv.f = f;
  unsigned u = cv.u;
  return (u16)((u + 0x7FFFu + ((u >> 16) & 1u)) >> 16);   // RNE
}
__device__ __forceinline__ float bf2f(u16 h) {
  union { unsigned u; float f; } cv; cv.u = ((unsigned)h) << 16;
  return cv.f;
}

// 64-lane sum via DPP (VALU-only). Result wave-uniform via readlane 63.
__device__ __forceinline__ float wredsum(float x) {
  x += __uint_as_float(__builtin_amdgcn_update_dpp(0u, __float_as_uint(x), 0x111, 0xf, 0xf, true));
  x += __uint_as_float(__builtin_amdgcn_update_dpp(0u, __float_as_uint(x), 0x112, 0xf, 0xf, true));
  x += __uint_as_float(__builtin_amdgcn_update_dpp(0u, __float_as_uint(x), 0x114, 0xf, 0xf, true));
  x += __uint_as_float(__builtin_amdgcn_update_dpp(0u, __float_as_uint(x), 0x118, 0xf, 0xf, true));
  x += __uint_as_float(__builtin_amdgcn_update_dpp(0u, __float_as_uint(x), 0x142, 0xa, 0xf, true));
  x += __uint_as_float(__builtin_amdgcn_update_dpp(0u, __float_as_uint(x), 0x143, 0xc, 0xf, true));
  return __uint_as_float(__builtin_amdgcn_readlane(__float_as_uint(x), 63));
}
__device__ __forceinline__ float lanebcast(float x, int l) {
  return __uint_as_float(__builtin_amdgcn_readlane(__float_as_uint(x), l));
}

// ---------------------------------------------------------------------------
// Megastep P: apply phase = r15 (unchanged); factorize = PAIRED
// owner-precompute: prologue derives pair (0,1); 15 barrier steps, each
// applying pair (2m,2m+1) via the correction d2' = d2 - f1*(vB^H vA)
// (3 independent dots -> reduces pipeline; ONE reduce-latency per TWO
// reflectors), owner wave w=m+1 derives pair (2m+2,2m+3) off-path.
// ---------------------------------------------------------------------------
template<int P>
__global__ __launch_bounds__(1024, 1) void qr_megastep(
    const float* __restrict__ ure_raw, const float* __restrict__ uim_raw,
    float2* __restrict__ A, float2* __restrict__ tau)
{
  const int tid = threadIdx.x, lane = tid & 63, w = tid >> 6;   // w 0..15
  const int role = blockIdx.x;
  __shared__ float2 sv32[32][256];
  __shared__ float2 sfin[32][256];
  __shared__ float2 snA[2][256];
  __shared__ float2 snB[2][256];
  __shared__ float4 sscalAB[2];      // (tauA.re, tauA.im, tauB.re, tauB.im)
  __shared__ float2 sg[2];           // g = vB^H vA
  __shared__ float2 stau32[32];
  __shared__ float2 stauOut[32];

  constexpr int J0P  = (P > 0) ? 32*(P-1) : 0;   // prev-panel start
  constexpr int RP   = 256 - J0P;
  constexpr int MCHP = (RP + 63) >> 6;
  constexpr int PIV  = (P == 0) ? 0 : 32;        // pivot row offset in window
  constexpr int J0W  = (P == 0) ? 0 : J0P;       // factorize window start
  constexpr int RW   = 256 - J0W;
  constexpr int MCHW = (RW + 63) >> 6;

  if constexpr (P == 0) {
    if (role > 0) {
      const int c0 = 32*role;
      const int c = tid & 31, r0 = tid >> 5;     // r0 0..31
      #pragma unroll
      for (int r8 = 0; r8 < 8; ++r8) {
        int r = r0 + r8*32;
        A[(size_t)(c0+c)*D_ + r] = make_float2(ure_raw[(size_t)r*D_ + c0 + c],
                                               uim_raw[(size_t)r*D_ + c0 + c]);
      }
      return;
    }
  }

  float2 col[2][4];

  if constexpr (P > 0) {
    // ---- stage V_{P-1} and taus; load own cols ----
    #pragma unroll
    for (int it = 0; it < 8; ++it) {
      int idx = it*1024 + tid;
      int c = idx >> 8, rr = idx & 255;
      float2 val = make_float2(0.f, 0.f);
      if (rr < RP) val = A[(size_t)(J0P+c)*D_ + J0P + rr];
      sv32[c][rr] = val;
    }
    if (tid < 32) stau32[tid] = tau[J0P + tid];
    const int c0 = (role > 0) ? 32*(P + role) : 32*P;
    #pragma unroll
    for (int lc = 0; lc < 2; ++lc) {
      int cg = c0 + 2*w + lc;
      #pragma unroll
      for (int m = 0; m < 4; ++m) {
        int rr = m*64 + lane;
        col[lc][m] = make_float2(0.f, 0.f);
        if (m < MCHP && rr < RP) col[lc][m] = A[(size_t)cg*D_ + J0P + rr];
      }
    }
    __syncthreads();

    // ---- fused reflector apply: 32 dependent steps, 2 cols/wave ----
    #pragma unroll 4
    for (int jl = 0; jl < 32; ++jl) {
      float2 tt = stau32[jl];
      float2 v[4];
      { float2 rv = sv32[jl][lane];
        v[0] = (lane > jl) ? rv : ((lane == jl) ? make_float2(1.f, 0.f)
                                                : make_float2(0.f, 0.f)); }
      #pragma unroll
      for (int m = 1; m < 4; ++m) v[m] = sv32[jl][m*64 + lane];
      float wr[2], wi[2];
      #pragma unroll
      for (int lc = 0; lc < 2; ++lc) {
        wr[lc] = 0.f; wi[lc] = 0.f;
        #pragma unroll
        for (int m = 0; m < 4; ++m) {
          if (m < MCHP) {
            float2 a = col[lc][m];
            wr[lc] += v[m].x*a.x + v[m].y*a.y;   // conj(v)*a
            wi[lc] += v[m].x*a.y - v[m].y*a.x;
          }
        }
      }
      #pragma unroll
      for (int lc = 0; lc < 2; ++lc) { wr[lc] = wredsum(wr[lc]);
                                       wi[lc] = wredsum(wi[lc]); }
      #pragma unroll
      for (int lc = 0; lc < 2; ++lc) {
        float fr = tt.x*wr[lc] + tt.y*wi[lc];    // f = conj(tau)*w
        float fi = tt.x*wi[lc] - tt.y*wr[lc];
        #pragma unroll
        for (int m = 0; m < 4; ++m) {
          if (m < MCHP) {
            col[lc][m].x -= fr*v[m].x - fi*v[m].y;
            col[lc][m].y -= fr*v[m].y + fi*v[m].x;
          }
        }
      }
    }

    if (role > 0) {
      #pragma unroll
      for (int lc = 0; lc < 2; ++lc) {
        int cg = 32*(P + role) + 2*w + lc;
        #pragma unroll
        for (int m = 0; m < 4; ++m) {
          int rr = m*64 + lane;
          if (m < MCHP && rr < RP) A[(size_t)cg*D_ + J0P + rr] = col[lc][m];
        }
      }
      return;
    }
    __syncthreads();
  } else {
    // P == 0, role 0: init panel 0 into registers (transposed raw read)
    #pragma unroll
    for (int lc = 0; lc < 2; ++lc) {
      int cg = 2*w + lc;
      #pragma unroll
      for (int m = 0; m < 4; ++m) {
        int rr = m*64 + lane;
        col[lc][m] = make_float2(ure_raw[(size_t)rr*D_ + cg],
                                 uim_raw[(size_t)rr*D_ + cg]);
      }
    }
  }

  // ===== role 0: factorize panel P, PAIRED owner-precompute =====
  // derive pair (jlA, jlA+1) from owner's cols ca,cb; publish to buffer buf.
  auto derive_pair = [&](float2 (&ca)[4], float2 (&cb)[4], int jlA, int buf) {
    const int prA = PIV + jlA, prB = prA + 1;    // pivot rows, both chunk 0
    // --- reflector A ---
    float part = (lane > prA) ? (ca[0].x*ca[0].x + ca[0].y*ca[0].y) : 0.f;
    if (1 < MCHW) part += ca[1].x*ca[1].x + ca[1].y*ca[1].y;
    if (2 < MCHW) part += ca[2].x*ca[2].x + ca[2].y*ca[2].y;
    if (3 < MCHW) part += ca[3].x*ca[3].x + ca[3].y*ca[3].y;
    part = wredsum(part);
    float ar = lanebcast(ca[0].x, prA), ai = lanebcast(ca[0].y, prA);
    float trA, tiA, sr, si, btA;
    if (part == 0.f && ai == 0.f) {
      trA = tiA = sr = si = 0.f; btA = ar;
    } else {
      float nrm = sqrtf(ar*ar + ai*ai + part);
      btA = (ar >= 0.f) ? -nrm : nrm;            // -SIGN(nrm, Re(alpha))
      trA = (btA - ar)/btA; tiA = -ai/btA;
      float dr = ar - btA, di = ai, dn = dr*dr + di*di;
      sr = dr/dn; si = -di/dn;                   // 1/(alpha-beta)
    }
    float2 vA[4];
    {
      float2 t0 = make_float2(ca[0].x*sr - ca[0].y*si, ca[0].x*si + ca[0].y*sr);
      vA[0] = (lane > prA) ? t0 : ((lane == prA) ? make_float2(1.f, 0.f)
                                                 : make_float2(0.f, 0.f));
    }
    vA[1] = make_float2(ca[1].x*sr - ca[1].y*si, ca[1].x*si + ca[1].y*sr);
    vA[2] = make_float2(ca[2].x*sr - ca[2].y*si, ca[2].x*si + ca[2].y*sr);
    vA[3] = make_float2(ca[3].x*sr - ca[3].y*si, ca[3].x*si + ca[3].y*sr);
    {
      float2 o0 = (lane < prA) ? ca[0]
                : ((lane == prA) ? make_float2(btA, 0.f) : vA[0]);
      sfin[jlA][lane] = o0;
      if (1 < MCHW) sfin[jlA][64 + lane]  = vA[1];
      if (2 < MCHW) sfin[jlA][128 + lane] = vA[2];
      if (3 < MCHW) sfin[jlA][192 + lane] = vA[3];
    }
    // --- apply H_A to cb ---
    {
      float wr_ = vA[0].x*cb[0].x + vA[0].y*cb[0].y;
      float wi_ = vA[0].x*cb[0].y - vA[0].y*cb[0].x;
      if (1 < MCHW) { wr_ += vA[1].x*cb[1].x + vA[1].y*cb[1].y;
                      wi_ += vA[1].x*cb[1].y - vA[1].y*cb[1].x; }
      if (2 < MCHW) { wr_ += vA[2].x*cb[2].x + vA[2].y*cb[2].y;
                      wi_ += vA[2].x*cb[2].y - vA[2].y*cb[2].x; }
      if (3 < MCHW) { wr_ += vA[3].x*cb[3].x + vA[3].y*cb[3].y;
                      wi_ += vA[3].x*cb[3].y - vA[3].y*cb[3].x; }
      wr_ = wredsum(wr_); wi_ = wredsum(wi_);
      float fr = trA*wr_ + tiA*wi_;              // conj(tauA)*w
      float fi = trA*wi_ - tiA*wr_;
      cb[0].x -= fr*vA[0].x - fi*vA[0].y; cb[0].y -= fr*vA[0].y + fi*vA[0].x;
      if (1 < MCHW) { cb[1].x -= fr*vA[1].x - fi*vA[1].y;
                      cb[1].y -= fr*vA[1].y + fi*vA[1].x; }
      if (2 < MCHW) { cb[2].x -= fr*vA[2].x - fi*vA[2].y;
                      cb[2].y -= fr*vA[2].y + fi*vA[2].x; }
      if (3 < MCHW) { cb[3].x -= fr*vA[3].x - fi*vA[3].y;
                      cb[3].y -= fr*vA[3].y + fi*vA[3].x; }
    }
    // --- reflector B ---
    float partB = (lane > prB) ? (cb[0].x*cb[0].x + cb[0].y*cb[0].y) : 0.f;
    if (1 < MCHW) partB += cb[1].x*cb[1].x + cb[1].y*cb[1].y;
    if (2 < MCHW) partB += cb[2].x*cb[2].x + cb[2].y*cb[2].y;
    if (3 < MCHW) partB += cb[3].x*cb[3].x + cb[3].y*cb[3].y;
    partB = wredsum(partB);
    float br_ = lanebcast(cb[0].x, prB), bi_ = lanebcast(cb[0].y, prB);
    float trB, tiB, srB, siB, btB;
    if (partB == 0.f && bi_ == 0.f) {
      trB = tiB = srB = siB = 0.f; btB = br_;
    } else {
      float nrm = sqrtf(br_*br_ + bi_*bi_ + partB);
      btB = (br_ >= 0.f) ? -nrm : nrm;
      trB = (btB - br_)/btB; tiB = -bi_/btB;
      float dr = br_ - btB, di = bi_, dn = dr*dr + di*di;
      srB = dr/dn; siB = -di/dn;
    }
    float2 vB[4];
    {
      float2 t0 = make_float2(cb[0].x*srB - cb[0].y*siB, cb[0].x*siB + cb[0].y*srB);
      vB[0] = (lane > prB) ? t0 : ((lane == prB) ? make_float2(1.f, 0.f)
                                                 : make_float2(0.f, 0.f));
    }
    vB[1] = make_float2(cb[1].x*srB - cb[1].y*siB, cb[1].x*siB + cb[1].y*srB);
    vB[2] = make_float2(cb[2].x*srB - cb[2].y*siB, cb[2].x*siB + cb[2].y*srB);
    vB[3] = make_float2(cb[3].x*srB - cb[3].y*siB, cb[3].x*siB + cb[3].y*srB);
    {
      float2 o0 = (lane < prB) ? cb[0]
                : ((lane == prB) ? make_float2(btB, 0.f) : vB[0]);
      sfin[jlA+1][lane] = o0;
      if (1 < MCHW) sfin[jlA+1][64 + lane]  = vB[1];
      if (2 < MCHW) sfin[jlA+1][128 + lane] = vB[2];
      if (3 < MCHW) sfin[jlA+1][192 + lane] = vB[3];
    }
    // --- g = vB^H vA ---
    float gr = vB[0].x*vA[0].x + vB[0].y*vA[0].y;
    float gi = vB[0].x*vA[0].y - vB[0].y*vA[0].x;
    if (1 < MCHW) { gr += vB[1].x*vA[1].x + vB[1].y*vA[1].y;
                    gi += vB[1].x*vA[1].y - vB[1].y*vA[1].x; }
    if (2 < MCHW) { gr += vB[2].x*vA[2].x + vB[2].y*vA[2].y;
                    gi += vB[2].x*vA[2].y - vB[2].y*vA[2].x; }
    if (3 < MCHW) { gr += vB[3].x*vA[3].x + vB[3].y*vA[3].y;
                    gi += vB[3].x*vA[3].y - vB[3].y*vA[3].x; }
    gr = wredsum(gr); gi = wredsum(gi);
    // --- publish ---
    snA[buf][lane] = vA[0]; snA[buf][64+lane] = vA[1];
    snA[buf][128+lane] = vA[2]; snA[buf][192+lane] = vA[3];
    snB[buf][lane] = vB[0]; snB[buf][64+lane] = vB[1];
    snB[buf][128+lane] = vB[2]; snB[buf][192+lane] = vB[3];
    if (lane == 0) {
      sscalAB[buf] = make_float4(trA, tiA, trB, tiB);
      sg[buf] = make_float2(gr, gi);
      stauOut[jlA]   = make_float2(trA, tiA);
      stauOut[jlA+1] = make_float2(trB, tiB);
    }
  };

  // prologue: wave 0 derives pair (0,1) -> buffer 0
  if (w == 0) derive_pair(col[0], col[1], 0, 0);
  __syncthreads();

  #pragma unroll 1
  for (int m = 0; m < 15; ++m) {
    const int cur = m & 1, nxt = cur ^ 1;
    float2 vA0 = snA[cur][lane],       vA1 = snA[cur][64 + lane],
           vA2 = snA[cur][128 + lane], vA3 = snA[cur][192 + lane];
    float2 vB0 = snB[cur][lane],       vB1 = snB[cur][64 + lane],
           vB2 = snB[cur][128 + lane], vB3 = snB[cur][192 + lane];
    float4 sc = sscalAB[cur];
    float2 g  = sg[cur];
    #pragma unroll
    for (int lc = 0; lc < 2; ++lc) {
      int cl = 2*w + lc;
      if (cl > 2*m + 1) {
        float d1r, d1i, d2r, d2i;
        { float2 a = col[lc][0];
          d1r = vA0.x*a.x + vA0.y*a.y; d1i = vA0.x*a.y - vA0.y*a.x;
          d2r = vB0.x*a.x + vB0.y*a.y; d2i = vB0.x*a.y - vB0.y*a.x; }
        if (1 < MCHW) { float2 a = col[lc][1];
          d1r += vA1.x*a.x + vA1.y*a.y; d1i += vA1.x*a.y - vA1.y*a.x;
          d2r += vB1.x*a.x + vB1.y*a.y; d2i += vB1.x*a.y - vB1.y*a.x; }
        if (2 < MCHW) { float2 a = col[lc][2];
          d1r += vA2.x*a.x + vA2.y*a.y; d1i += vA2.x*a.y - vA2.y*a.x;
          d2r += vB2.x*a.x + vB2.y*a.y; d2i += vB2.x*a.y - vB2.y*a.x; }
        if (3 < MCHW) { float2 a = col[lc][3];
          d1r += vA3.x*a.x + vA3.y*a.y; d1i += vA3.x*a.y - vA3.y*a.x;
          d2r += vB3.x*a.x + vB3.y*a.y; d2i += vB3.x*a.y - vB3.y*a.x; }
        d1r = wredsum(d1r); d1i = wredsum(d1i);
        d2r = wredsum(d2r); d2i = wredsum(d2i);
        float f1r = sc.x*d1r + sc.y*d1i;           // conj(tauA)*d1
        float f1i = sc.x*d1i - sc.y*d1r;
        float d2cr = d2r - (f1r*g.x - f1i*g.y);    // d2 - f1*g
        float d2ci = d2i - (f1r*g.y + f1i*g.x);
        float f2r = sc.z*d2cr + sc.w*d2ci;         // conj(tauB)*d2'
        float f2i = sc.z*d2ci - sc.w*d2cr;
        { col[lc][0].x -= f1r*vA0.x - f1i*vA0.y + f2r*vB0.x - f2i*vB0.y;
          col[lc][0].y -= f1r*vA0.y + f1i*vA0.x + f2r*vB0.y + f2i*vB0.x; }
        if (1 < MCHW) {
          col[lc][1].x -= f1r*vA1.x - f1i*vA1.y + f2r*vB1.x - f2i*vB1.y;
          col[lc][1].y -= f1r*vA1.y + f1i*vA1.x + f2r*vB1.y + f2i*vB1.x; }
        if (2 < MCHW) {
          col[lc][2].x -= f1r*vA2.x - f1i*vA2.y + f2r*vB2.x - f2i*vB2.y;
          col[lc][2].y -= f1r*vA2.y + f1i*vA2.x + f2r*vB2.y + f2i*vB2.x; }
        if (3 < MCHW) {
          col[lc][3].x -= f1r*vA3.x - f1i*vA3.y + f2r*vB3.x - f2i*vB3.y;
          col[lc][3].y -= f1r*vA3.y + f1i*vA3.x + f2r*vB3.y + f2i*vB3.x; }
      }
    }
    if (w == m + 1) derive_pair(col[0], col[1], 2*m + 2, nxt);
    __syncthreads();
  }

  // ---- batch-write panel columns + taus to global ----
  #pragma unroll
  for (int it = 0; it < 8; ++it) {
    int idx = it*1024 + tid;
    int c = idx >> 8, rr = idx & 255;
    if (rr < RW) A[(size_t)(32*P + c)*D_ + J0W + rr] = sfin[c][rr];
  }
  if (tid < 32) tau[32*P + tid] = stauOut[tid];
}

// ---------------------------------------------------------------------------
// zung2r, PAIRED: column c of Q; per iteration apply H_i, H_{i-1} together
// (d1, d2, g dots reduce in parallel -> one reduce-latency per 2 reflectors).
// Depth-4 prefetch ring. Epilogue writes bf16 B^T matrices.
// ---------------------------------------------------------------------------
__global__ __launch_bounds__(256, 1) void qr_bwd_kernel(
    const float2* __restrict__ A, const float2* __restrict__ tau,
    u16* __restrict__ Benc, u16* __restrict__ Bdec)
{
  const int lane = threadIdx.x & 63;
  const int w = threadIdx.x >> 6;
  const int c = blockIdx.x * 4 + w;          // column 0..255
  __shared__ float2 stau[256];
  if (threadIdx.x < 256) stau[threadIdx.x] = tau[threadIdx.x];
  __syncthreads();

  float2 q[4];
  #pragma unroll
  for (int m = 0; m < 4; ++m) {
    q[m] = make_float2(0.f, 0.f);
    if (m*64 + lane == c) q[m].x = 1.f;      // q = e_c
  }
  float2 A0[4], A1[4], A2[4], A3[4];
  {
    int i0 = c, i1 = (c >= 1) ? c-1 : 0, i2 = (c >= 2) ? c-2 : 0,
        i3 = (c >= 3) ? c-3 : 0;
    #pragma unroll
    for (int m = 0; m < 4; ++m) {
      A0[m] = A[(size_t)i0*D_ + m*64 + lane];
      A1[m] = A[(size_t)i1*D_ + m*64 + lane];
      A2[m] = A[(size_t)i2*D_ + m*64 + lane];
      A3[m] = A[(size_t)i3*D_ + m*64 + lane];
    }
  }

  int i = c;
  #pragma unroll 1
  while (i >= 1) {                           // pair (i, i-1)
    float2 ta = stau[i], tb = stau[i-1];
    float2 vI[4], vJ[4];
    #pragma unroll
    for (int m = 0; m < 4; ++m) {
      int r = m*64 + lane;
      vI[m] = (r > i)   ? A0[m] : ((r == i)   ? make_float2(1.f, 0.f)
                                              : make_float2(0.f, 0.f));
      vJ[m] = (r > i-1) ? A1[m] : ((r == i-1) ? make_float2(1.f, 0.f)
                                              : make_float2(0.f, 0.f));
    }
    // prefetch cols i-4, i-5
    float2 P0[4], P1[4];
    {
      int n0 = (i >= 4) ? i-4 : 0, n1 = (i >= 5) ? i-5 : 0;
      #pragma unroll
      for (int m = 0; m < 4; ++m) {
        P0[m] = A[(size_t)n0*D_ + m*64 + lane];
        P1[m] = A[(size_t)n1*D_ + m*64 + lane];
      }
    }
    float d1r = 0.f, d1i = 0.f, d2r = 0.f, d2i = 0.f, gr = 0.f, gi = 0.f;
    #pragma unroll
    for (int m = 0; m < 4; ++m) {
      d1r += vI[m].x*q[m].x + vI[m].y*q[m].y;    // conj(vI)*q
      d1i += vI[m].x*q[m].y - vI[m].y*q[m].x;
      d2r += vJ[m].x*q[m].x + vJ[m].y*q[m].y;    // conj(vJ)*q
      d2i += vJ[m].x*q[m].y - vJ[m].y*q[m].x;
      gr  += vJ[m].x*vI[m].x + vJ[m].y*vI[m].y;  // conj(vJ)*vI
      gi  += vJ[m].x*vI[m].y - vJ[m].y*vI[m].x;
    }
    d1r = wredsum(d1r); d1i = wredsum(d1i);
    d2r = wredsum(d2r); d2i = wredsum(d2i);
    gr  = wredsum(gr);  gi  = wredsum(gi);
    float f1r = ta.x*d1r - ta.y*d1i;             // f1 = tauI*d1 (non-conj)
    float f1i = ta.x*d1i + ta.y*d1r;
    float d2cr = d2r - (f1r*gr - f1i*gi);        // d2 - f1*g
    float d2ci = d2i - (f1r*gi + f1i*gr);
    float f2r = tb.x*d2cr - tb.y*d2ci;           // f2 = tauJ*d2'
    float f2i = tb.x*d2ci + tb.y*d2cr;
    #pragma unroll
    for (int m = 0; m < 4; ++m) {
      q[m].x -= f1r*vI[m].x - f1i*vI[m].y + f2r*vJ[m].x - f2i*vJ[m].y;
      q[m].y -= f1r*vI[m].y + f1i*vI[m].x + f2r*vJ[m].y + f2i*vJ[m].x;
      A0[m] = A2[m]; A1[m] = A3[m]; A2[m] = P0[m]; A3[m] = P1[m];
    }
    i -= 2;
  }
  if (i == 0) {                                 // leftover reflector 0
    float2 tt = stau[0];
    float2 v0[4];
    #pragma unroll
    for (int m = 0; m < 4; ++m) {
      int r = m*64 + lane;
      v0[m] = (r > 0) ? A0[m] : make_float2(1.f, 0.f);   // r==0 -> 1
    }
    float wr = 0.f, wi = 0.f;
    #pragma unroll
    for (int m = 0; m < 4; ++m) {
      wr += v0[m].x*q[m].x + v0[m].y*q[m].y;
      wi += v0[m].x*q[m].y - v0[m].y*q[m].x;
    }
    wr = wredsum(wr); wi = wredsum(wi);
    float fr = tt.x*wr - tt.y*wi;
    float fi = tt.x*wi + tt.y*wr;
    #pragma unroll
    for (int m = 0; m < 4; ++m) {
      q[m].x -= fr*v0[m].x - fi*v0[m].y;
      q[m].y -= fr*v0[m].y + fi*v0[m].x;
    }
  }

  #pragma unroll
  for (int m = 0; m < 4; ++m) {
    int r = m*64 + lane;
    u16 qre = f2bf(q[m].x), qim = f2bf(q[m].y), qimn = f2bf(-q[m].y);
    Benc[(size_t)c*D_ + r]              = qre;
    Benc[(size_t)(c+256)*D_ + r]        = qim;
    Bdec[(size_t)c*512 + r]             = qre;
    Bdec[(size_t)c*512 + 256 + r]       = qimn;
    Bdec[(size_t)(c+256)*512 + r]       = qim;
    Bdec[(size_t)(c+256)*512 + 256 + r] = qre;
  }
}

// ---------------------------------------------------------------------------
// Per-(b,t,d) coefficient tables (L2-resident; keeps scan memory-bound).
// ---------------------------------------------------------------------------
__global__ __launch_bounds__(256) void coef_kernel(
  const float* __restrict__ dt, const float* __restrict__ lam_re, const float* __restrict__ lam_im,
  const float* __restrict__ noise_raw,
  float* __restrict__ c_dre, float* __restrict__ c_dim, float* __restrict__ c_fre,
  float* __restrict__ c_fim, float* __restrict__ c_ns)
{
  int bt = blockIdx.x; int d = threadIdx.x;
  float dtv = dt[bt];
  float lr = lam_re[d], li = lam_im[d];
  float lam_r = fmaxf(-log1pf(expf(-lr)), -0.3f);     // -softplus(-x), clamp
  float ar = dtv*lam_r, ai = dtv*li;
  float er = expf(ar);
  float dre = er*cosf(ai), dim_ = er*sinf(ai);
  float t = lam_r + 1e-12f;
  float sgn = (t > 0.f) ? 1.f : ((t < 0.f) ? -1.f : 0.f);
  float den_re = lam_r + 1e-8f*sgn, den_im = li;      // lam_safe
  float nr = dre - 1.f, ni = dim_;
  float d2 = den_re*den_re + den_im*den_im;
  float fre = (nr*den_re + ni*den_im)/d2;
  float fim = (ni*den_re - nr*den_im)/d2;
  float ns = sqrtf(fmaxf(dtv,0.f)) * log1pf(expf(noise_raw[d])) * 0.01f;
  int idx = bt*D_+d;
  c_dre[idx]=dre; c_dim[idx]=dim_; c_fre[idx]=fre; c_fim[idx]=fim; c_ns[idx]=ns;
}

// ---------------------------------------------------------------------------
// bf16 MFMA GEMM, 128x128 tile, 4 waves, BK=64, 16x16x32 MFMA.
// encode_gemm reads fp32 x directly and converts during staging.
// ---------------------------------------------------------------------------
#define LDT 72

__global__ __launch_bounds__(256) void encode_gemm(
    const float* __restrict__ x, const u16* __restrict__ Bt,
    u16* __restrict__ xer16, u16* __restrict__ xei16)
{
  __shared__ u16 sA[128*LDT];
  __shared__ u16 sB[128*LDT];
  const int tid = threadIdx.x;
  const int lane = tid & 63, w = tid >> 6;
  const int wr = w >> 1, wc = w & 1;
  const int l15 = lane & 15, l4 = lane >> 4;
  const int m0 = blockIdx.x * 128;
  const int n0 = blockIdx.y * 128;
  f32x4 acc[4][4] = {};
  for (int kb = 0; kb < 4; ++kb) {
    #pragma unroll
    for (int i = 0; i < 4; ++i) {
      int chunk = i*256 + tid;
      int row = chunk >> 3, k0 = (chunk & 7) * 8;
      const float* xs = x + (size_t)(m0+row)*D_ + kb*64 + k0;
      float4 f0 = *(const float4*)xs;
      float4 f1 = *(const float4*)(xs + 4);
      int4 va;
      va.x = (int)((unsigned)f2bf(f0.x) | ((unsigned)f2bf(f0.y) << 16));
      va.y = (int)((unsigned)f2bf(f0.z) | ((unsigned)f2bf(f0.w) << 16));
      va.z = (int)((unsigned)f2bf(f1.x) | ((unsigned)f2bf(f1.y) << 16));
      va.w = (int)((unsigned)f2bf(f1.z) | ((unsigned)f2bf(f1.w) << 16));
      int4 vb = *(const int4*)(Bt + (size_t)(n0+row)*D_ + kb*64 + k0);
      *(int4*)&sA[row*LDT + k0] = va;
      *(int4*)&sB[row*LDT + k0] = vb;
    }
    __syncthreads();
    #pragma unroll
    for (int ks = 0; ks < 2; ++ks) {
      bf16x8 af[4], bb[4];
      #pragma unroll
      for (int mf = 0; mf < 4; ++mf)
        af[mf] = *(const bf16x8*)&sA[(wr*64 + mf*16 + l15)*LDT + ks*32 + l4*8];
      #pragma unroll
      for (int nf = 0; nf < 4; ++nf)
        bb[nf] = *(const bf16x8*)&sB[(wc*64 + nf*16 + l15)*LDT + ks*32 + l4*8];
      #pragma unroll
      for (int mf = 0; mf < 4; ++mf)
        #pragma unroll
        for (int nf = 0; nf < 4; ++nf)
          acc[mf][nf] = __builtin_amdgcn_mfma_f32_16x16x32_bf16(
              af[mf], bb[nf], acc[mf][nf], 0, 0, 0);
    }
    __syncthreads();
  }
  #pragma unroll
  for (int mf = 0; mf < 4; ++mf)
    #pragma unroll
    for (int nf = 0; nf < 4; ++nf)
      #pragma unroll
      for (int r = 0; r < 4; ++r) {
        int row = m0 + wr*64 + mf*16 + l4*4 + r;
        int col = n0 + wc*64 + nf*16 + l15;
        float v = acc[mf][nf][r];
        if (col < 256) xer16[(size_t)row*D_ + col] = f2bf(v);
        else           xei16[(size_t)row*D_ + col - 256] = f2bf(-v);
      }
}

__global__ __launch_bounds__(256) void decode_gemm(
    const u16* __restrict__ hre16, const u16* __restrict__ him16,
    const u16* __restrict__ Bt, float* __restrict__ out)
{
  __shared__ u16 sA[128*LDT];
  __shared__ u16 sB[128*LDT];
  const int tid = threadIdx.x;
  const int lane = tid & 63, w = tid >> 6;
  const int wr = w >> 1, wc = w & 1;
  const int l15 = lane & 15, l4 = lane >> 4;
  const int m0 = blockIdx.x * 128;
  const int n0 = blockIdx.y * 128;
  f32x4 acc[4][4] = {};
  for (int kb = 0; kb < 8; ++kb) {
    const u16* aplane = (kb < 4) ? hre16 : him16;
    const int kk = (kb & 3) * 64;
    #pragma unroll
    for (int i = 0; i < 4; ++i) {
      int chunk = i*256 + tid;
      int row = chunk >> 3, k0 = (chunk & 7) * 8;
      int4 va = *(const int4*)(aplane + (size_t)(m0+row)*D_ + kk + k0);
      int4 vb = *(const int4*)(Bt + (size_t)(n0+row)*512 + kb*64 + k0);
      *(int4*)&sA[row*LDT + k0] = va;
      *(int4*)&sB[row*LDT + k0] = vb;
    }
    __syncthreads();
    #pragma unroll
    for (int ks = 0; ks < 2; ++ks) {
      bf16x8 af[4], bb[4];
      #pragma unroll
      for (int mf = 0; mf < 4; ++mf)
        af[mf] = *(const bf16x8*)&sA[(wr*64 + mf*16 + l15)*LDT + ks*32 + l4*8];
      #pragma unroll
      for (int nf = 0; nf < 4; ++nf)
        bb[nf] = *(const bf16x8*)&sB[(wc*64 + nf*16 + l15)*LDT + ks*32 + l4*8];
      #pragma unroll
      for (int mf = 0; mf < 4; ++mf)
        #pragma unroll
        for (int nf = 0; nf < 4; ++nf)
          acc[mf][nf] = __builtin_amdgcn_mfma_f32_16x16x32_bf16(
              af[mf], bb[nf], acc[mf][nf], 0, 0, 0);
    }
    __syncthreads();
  }
  #pragma unroll
  for (int mf = 0; mf < 4; ++mf)
    #pragma unroll
    for (int nf = 0; nf < 4; ++nf)
      #pragma unroll
      for (int r = 0; r < 4; ++r) {
        int row = m0 + wr*64 + mf*16 + l4*4 + r;
        int col = n0 + wc*64 + nf*16 + l15;
        float v = acc[mf][nf][r];
        if (col < 256) out[(size_t)row*D_ + col] = v;
        else           out[PLANE + (size_t)row*D_ + col - 256] = v;
      }
}

// ---------------------------------------------------------------------------
// Scan: reads bf16 x_enc planes + fp32 eps + coef tables (L2-resident);
// writes bf16 h planes. One block per (b,n); thread = d. Memory-bound.
// ---------------------------------------------------------------------------
__global__ __launch_bounds__(256) void scan_kernel(
  const float* __restrict__ eps,
  const float* __restrict__ c_dre, const float* __restrict__ c_dim,
  const float* __restrict__ c_fre, const float* __restrict__ c_fim, const float* __restrict__ c_ns,
  const u16* __restrict__ xer16, const u16* __restrict__ xei16,
  u16* __restrict__ hre16, u16* __restrict__ him16)
{
  int bx = blockIdx.x;
  int b = bx >> 9, n = bx & 511;
  int d = threadIdx.x;
  float hr = 0.f, hi = 0.f;
  for (int t = 0; t < T_; ++t) {
    int bt = b*T_ + t;
    int cidx = bt*D_ + d;
    float dre = c_dre[cidx], dim_ = c_dim[cidx];
    float fre = c_fre[cidx], fim = c_fim[cidx];
    float ns  = c_ns[cidx];
    size_t idx = ((size_t)bt*N_ + n)*D_ + d;
    float xr = bf2f(xer16[idx]), xi = bf2f(xei16[idx]), ep = eps[idx];
    float br = fre*xr - fim*xi + ep*ns;
    float bi = fre*xi + fim*xr;
    float nr2 = dre*hr - dim_*hi + br;
    float ni2 = dre*hi + dim_*hr + bi;
    hr = nr2; hi = ni2;
    hre16[idx] = f2bf(hr); him16[idx] = f2bf(hi);
  }
}

// ---------------------------------------------------------------------------
extern "C" void kernel_launch(void* const* d_in, const int* in_sizes, int n_in,
                              void* d_out, int out_size, void* d_ws, size_t ws_size,
                              hipStream_t stream)
{
  const float* x         = (const float*)d_in[0];
  const float* dt        = (const float*)d_in[1];
  const float* eps       = (const float*)d_in[2];
  const float* ure_raw   = (const float*)d_in[3];
  const float* uim_raw   = (const float*)d_in[4];
  const float* lam_re    = (const float*)d_in[5];
  const float* lam_im    = (const float*)d_in[6];
  const float* noise_raw = (const float*)d_in[7];
  float* out = (float*)d_out;

  // ws layout (132 MB total):
  //   0       A float2[65536]            512 KB
  //   512K    tau float2[256]            2 KB
  //   1M      Benc bf16 [512][256]       256 KB
  //   1.5M    Bdec bf16 [512][512]       512 KB
  //   2M      coef tables 5 x 128 KB     640 KB
  //   4M      hre16 bf16 [M][256] 32 MB
  //   36M     xer16 32 MB
  //   68M     xei16 32 MB
  //   100M    him16 32 MB
  char* ws = (char*)d_ws;
  float2* A    = (float2*)(ws);
  float2* tau  = (float2*)(ws + 524288);
  u16* Benc    = (u16*)(ws + (1<<20));
  u16* Bdec    = (u16*)(ws + 1572864);
  float* c_dre = (float*)(ws + (2<<20));
  float* c_dim = c_dre + B_*T_*D_;
  float* c_fre = c_dim + B_*T_*D_;
  float* c_fim = c_fre + B_*T_*D_;
  float* c_ns  = c_fim + B_*T_*D_;
  u16* hre16   = (u16*)(ws + ((size_t)4<<20));
  u16* xer16   = (u16*)(ws + ((size_t)36<<20));
  u16* xei16   = (u16*)(ws + ((size_t)68<<20));
  u16* him16   = (u16*)(ws + ((size_t)100<<20));

  qr_megastep<0><<<8, 1024, 0, stream>>>(ure_raw, uim_raw, A, tau);
  qr_megastep<1><<<7, 1024, 0, stream>>>(ure_raw, uim_raw, A, tau);
  qr_megastep<2><<<6, 1024, 0, stream>>>(ure_raw, uim_raw, A, tau);
  qr_megastep<3><<<5, 1024, 0, stream>>>(ure_raw, uim_raw, A, tau);
  qr_megastep<4><<<4, 1024, 0, stream>>>(ure_raw, uim_raw, A, tau);
  qr_megastep<5><<<3, 1024, 0, stream>>>(ure_raw, uim_raw, A, tau);
  qr_megastep<6><<<2, 1024, 0, stream>>>(ure_raw, uim_raw, A, tau);
  qr_megastep<7><<<1, 1024, 0, stream>>>(ure_raw, uim_raw, A, tau);
  qr_bwd_kernel<<<64, 256, 0, stream>>>(A, tau, Benc, Bdec);
  coef_kernel<<<B_*T_, 256, 0, stream>>>(dt, lam_re, lam_im, noise_raw,
                                         c_dre, c_dim, c_fre, c_fim, c_ns);
  encode_gemm<<<dim3(M_/128, 4), 256, 0, stream>>>(x, Benc, xer16, xei16);
  scan_kernel<<<B_*N_, 256, 0, stream>>>(eps, c_dre, c_dim, c_fre, c_fim, c_ns,
                                         xer16, xei16, hre16, him16);
  decode_gemm<<<dim3(M_/128, 4), 256, 0, stream>>>(hre16, him16, Bdec, out);
}

// Round 17
// 709.075 us; speedup vs baseline: 1.8497x; 1.0308x over previous
//
#include <hip/hip_runtime.h>
#include <math.h>

// Problem constants (B,T,N,D) = (2,64,512,256)
#define B_ 2
#define T_ 64
#define N_ 512
#define D_ 256
#define M_ (B_*T_*N_)            // 65536 rows for the GEMMs
#define PLANE ((size_t)M_*D_)    // 16777216 elements per output plane

typedef unsigned short u16;
typedef __attribute__((ext_vector_type(8))) short bf16x8;
typedef __attribute__((ext_vector_type(4))) float f32x4;

__device__ __forceinline__ u16 f2bf(float f) {
  union { float f; unsigned u; } cv; cv.f = f;
  unsigned u = cv.u;
  return (u16)((u + 0x7FFFu + ((u >> 16) & 1u)) >> 16);   // RNE
}
__device__ __forceinline__ float bf2f(u16 h) {
  union { unsigned u; float f; } cv; cv.u = ((unsigned)h) << 16;
  return cv.f;
}

// 64-lane sum via DPP (VALU-only). Result wave-uniform via readlane 63.
__device__ __forceinline__ float wredsum(float x) {
  x += __uint_as_float(__builtin_amdgcn_update_dpp(0u, __float_as_uint(x), 0x111, 0xf, 0xf, true));
  x += __uint_as_float(__builtin_amdgcn_update_dpp(0u, __float_as_uint(x), 0x112, 0xf, 0xf, true));
  x += __uint_as_float(__builtin_amdgcn_update_dpp(0u, __float_as_uint(x), 0x114, 0xf, 0xf, true));
  x += __uint_as_float(__builtin_amdgcn_update_dpp(0u, __float_as_uint(x), 0x118, 0xf, 0xf, true));
  x += __uint_as_float(__builtin_amdgcn_update_dpp(0u, __float_as_uint(x), 0x142, 0xa, 0xf, true));
  x += __uint_as_float(__builtin_amdgcn_update_dpp(0u, __float_as_uint(x), 0x143, 0xc, 0xf, true));
  return __uint_as_float(__builtin_amdgcn_readlane(__float_as_uint(x), 63));
}
__device__ __forceinline__ float lanebcast(float x, int l) {
  return __uint_as_float(__builtin_amdgcn_readlane(__float_as_uint(x), l));
}

// ---------------------------------------------------------------------------
// Megastep P (r16 paired owner-precompute factorize; apply = r15).
// ---------------------------------------------------------------------------
template<int P>
__global__ __launch_bounds__(1024, 1) void qr_megastep(
    const float* __restrict__ ure_raw, const float* __restrict__ uim_raw,
    float2* __restrict__ A, float2* __restrict__ tau)
{
  const int tid = threadIdx.x, lane = tid & 63, w = tid >> 6;   // w 0..15
  const int role = blockIdx.x;
  __shared__ float2 sv32[32][256];
  __shared__ float2 sfin[32][256];
  __shared__ float2 snA[2][256];
  __shared__ float2 snB[2][256];
  __shared__ float4 sscalAB[2];      // (tauA.re, tauA.im, tauB.re, tauB.im)
  __shared__ float2 sg[2];           // g = vB^H vA
  __shared__ float2 stau32[32];
  __shared__ float2 stauOut[32];

  constexpr int J0P  = (P > 0) ? 32*(P-1) : 0;   // prev-panel start
  constexpr int RP   = 256 - J0P;
  constexpr int MCHP = (RP + 63) >> 6;
  constexpr int PIV  = (P == 0) ? 0 : 32;        // pivot row offset in window
  constexpr int J0W  = (P == 0) ? 0 : J0P;       // factorize window start
  constexpr int RW   = 256 - J0W;
  constexpr int MCHW = (RW + 63) >> 6;

  if constexpr (P == 0) {
    if (role > 0) {
      const int c0 = 32*role;
      const int c = tid & 31, r0 = tid >> 5;     // r0 0..31
      #pragma unroll
      for (int r8 = 0; r8 < 8; ++r8) {
        int r = r0 + r8*32;
        A[(size_t)(c0+c)*D_ + r] = make_float2(ure_raw[(size_t)r*D_ + c0 + c],
                                               uim_raw[(size_t)r*D_ + c0 + c]);
      }
      return;
    }
  }

  float2 col[2][4];

  if constexpr (P > 0) {
    // ---- stage V_{P-1} and taus; load own cols ----
    #pragma unroll
    for (int it = 0; it < 8; ++it) {
      int idx = it*1024 + tid;
      int c = idx >> 8, rr = idx & 255;
      float2 val = make_float2(0.f, 0.f);
      if (rr < RP) val = A[(size_t)(J0P+c)*D_ + J0P + rr];
      sv32[c][rr] = val;
    }
    if (tid < 32) stau32[tid] = tau[J0P + tid];
    const int c0 = (role > 0) ? 32*(P + role) : 32*P;
    #pragma unroll
    for (int lc = 0; lc < 2; ++lc) {
      int cg = c0 + 2*w + lc;
      #pragma unroll
      for (int m = 0; m < 4; ++m) {
        int rr = m*64 + lane;
        col[lc][m] = make_float2(0.f, 0.f);
        if (m < MCHP && rr < RP) col[lc][m] = A[(size_t)cg*D_ + J0P + rr];
      }
    }
    __syncthreads();

    // ---- fused reflector apply: 32 dependent steps, 2 cols/wave ----
    #pragma unroll 4
    for (int jl = 0; jl < 32; ++jl) {
      float2 tt = stau32[jl];
      float2 v[4];
      { float2 rv = sv32[jl][lane];
        v[0] = (lane > jl) ? rv : ((lane == jl) ? make_float2(1.f, 0.f)
                                                : make_float2(0.f, 0.f)); }
      #pragma unroll
      for (int m = 1; m < 4; ++m) v[m] = sv32[jl][m*64 + lane];
      float wr[2], wi[2];
      #pragma unroll
      for (int lc = 0; lc < 2; ++lc) {
        wr[lc] = 0.f; wi[lc] = 0.f;
        #pragma unroll
        for (int m = 0; m < 4; ++m) {
          if (m < MCHP) {
            float2 a = col[lc][m];
            wr[lc] += v[m].x*a.x + v[m].y*a.y;   // conj(v)*a
            wi[lc] += v[m].x*a.y - v[m].y*a.x;
          }
        }
      }
      #pragma unroll
      for (int lc = 0; lc < 2; ++lc) { wr[lc] = wredsum(wr[lc]);
                                       wi[lc] = wredsum(wi[lc]); }
      #pragma unroll
      for (int lc = 0; lc < 2; ++lc) {
        float fr = tt.x*wr[lc] + tt.y*wi[lc];    // f = conj(tau)*w
        float fi = tt.x*wi[lc] - tt.y*wr[lc];
        #pragma unroll
        for (int m = 0; m < 4; ++m) {
          if (m < MCHP) {
            col[lc][m].x -= fr*v[m].x - fi*v[m].y;
            col[lc][m].y -= fr*v[m].y + fi*v[m].x;
          }
        }
      }
    }

    if (role > 0) {
      #pragma unroll
      for (int lc = 0; lc < 2; ++lc) {
        int cg = 32*(P + role) + 2*w + lc;
        #pragma unroll
        for (int m = 0; m < 4; ++m) {
          int rr = m*64 + lane;
          if (m < MCHP && rr < RP) A[(size_t)cg*D_ + J0P + rr] = col[lc][m];
        }
      }
      return;
    }
    __syncthreads();
  } else {
    // P == 0, role 0: init panel 0 into registers (transposed raw read)
    #pragma unroll
    for (int lc = 0; lc < 2; ++lc) {
      int cg = 2*w + lc;
      #pragma unroll
      for (int m = 0; m < 4; ++m) {
        int rr = m*64 + lane;
        col[lc][m] = make_float2(ure_raw[(size_t)rr*D_ + cg],
                                 uim_raw[(size_t)rr*D_ + cg]);
      }
    }
  }

  // ===== role 0: factorize panel P, PAIRED owner-precompute =====
  auto derive_pair = [&](float2 (&ca)[4], float2 (&cb)[4], int jlA, int buf) {
    const int prA = PIV + jlA, prB = prA + 1;    // pivot rows, both chunk 0
    // --- reflector A ---
    float part = (lane > prA) ? (ca[0].x*ca[0].x + ca[0].y*ca[0].y) : 0.f;
    if (1 < MCHW) part += ca[1].x*ca[1].x + ca[1].y*ca[1].y;
    if (2 < MCHW) part += ca[2].x*ca[2].x + ca[2].y*ca[2].y;
    if (3 < MCHW) part += ca[3].x*ca[3].x + ca[3].y*ca[3].y;
    part = wredsum(part);
    float ar = lanebcast(ca[0].x, prA), ai = lanebcast(ca[0].y, prA);
    float trA, tiA, sr, si, btA;
    if (part == 0.f && ai == 0.f) {
      trA = tiA = sr = si = 0.f; btA = ar;
    } else {
      float nrm = sqrtf(ar*ar + ai*ai + part);
      btA = (ar >= 0.f) ? -nrm : nrm;            // -SIGN(nrm, Re(alpha))
      trA = (btA - ar)/btA; tiA = -ai/btA;
      float dr = ar - btA, di = ai, dn = dr*dr + di*di;
      sr = dr/dn; si = -di/dn;                   // 1/(alpha-beta)
    }
    float2 vA[4];
    {
      float2 t0 = make_float2(ca[0].x*sr - ca[0].y*si, ca[0].x*si + ca[0].y*sr);
      vA[0] = (lane > prA) ? t0 : ((lane == prA) ? make_float2(1.f, 0.f)
                                                 : make_float2(0.f, 0.f));
    }
    vA[1] = make_float2(ca[1].x*sr - ca[1].y*si, ca[1].x*si + ca[1].y*sr);
    vA[2] = make_float2(ca[2].x*sr - ca[2].y*si, ca[2].x*si + ca[2].y*sr);
    vA[3] = make_float2(ca[3].x*sr - ca[3].y*si, ca[3].x*si + ca[3].y*sr);
    {
      float2 o0 = (lane < prA) ? ca[0]
                : ((lane == prA) ? make_float2(btA, 0.f) : vA[0]);
      sfin[jlA][lane] = o0;
      if (1 < MCHW) sfin[jlA][64 + lane]  = vA[1];
      if (2 < MCHW) sfin[jlA][128 + lane] = vA[2];
      if (3 < MCHW) sfin[jlA][192 + lane] = vA[3];
    }
    // --- apply H_A to cb ---
    {
      float wr_ = vA[0].x*cb[0].x + vA[0].y*cb[0].y;
      float wi_ = vA[0].x*cb[0].y - vA[0].y*cb[0].x;
      if (1 < MCHW) { wr_ += vA[1].x*cb[1].x + vA[1].y*cb[1].y;
                      wi_ += vA[1].x*cb[1].y - vA[1].y*cb[1].x; }
      if (2 < MCHW) { wr_ += vA[2].x*cb[2].x + vA[2].y*cb[2].y;
                      wi_ += vA[2].x*cb[2].y - vA[2].y*cb[2].x; }
      if (3 < MCHW) { wr_ += vA[3].x*cb[3].x + vA[3].y*cb[3].y;
                      wi_ += vA[3].x*cb[3].y - vA[3].y*cb[3].x; }
      wr_ = wredsum(wr_); wi_ = wredsum(wi_);
      float fr = trA*wr_ + tiA*wi_;              // conj(tauA)*w
      float fi = trA*wi_ - tiA*wr_;
      cb[0].x -= fr*vA[0].x - fi*vA[0].y; cb[0].y -= fr*vA[0].y + fi*vA[0].x;
      if (1 < MCHW) { cb[1].x -= fr*vA[1].x - fi*vA[1].y;
                      cb[1].y -= fr*vA[1].y + fi*vA[1].x; }
      if (2 < MCHW) { cb[2].x -= fr*vA[2].x - fi*vA[2].y;
                      cb[2].y -= fr*vA[2].y + fi*vA[2].x; }
      if (3 < MCHW) { cb[3].x -= fr*vA[3].x - fi*vA[3].y;
                      cb[3].y -= fr*vA[3].y + fi*vA[3].x; }
    }
    // --- reflector B ---
    float partB = (lane > prB) ? (cb[0].x*cb[0].x + cb[0].y*cb[0].y) : 0.f;
    if (1 < MCHW) partB += cb[1].x*cb[1].x + cb[1].y*cb[1].y;
    if (2 < MCHW) partB += cb[2].x*cb[2].x + cb[2].y*cb[2].y;
    if (3 < MCHW) partB += cb[3].x*cb[3].x + cb[3].y*cb[3].y;
    partB = wredsum(partB);
    float br_ = lanebcast(cb[0].x, prB), bi_ = lanebcast(cb[0].y, prB);
    float trB, tiB, srB, siB, btB;
    if (partB == 0.f && bi_ == 0.f) {
      trB = tiB = srB = siB = 0.f; btB = br_;
    } else {
      float nrm = sqrtf(br_*br_ + bi_*bi_ + partB);
      btB = (br_ >= 0.f) ? -nrm : nrm;
      trB = (btB - br_)/btB; tiB = -bi_/btB;
      float dr = br_ - btB, di = bi_, dn = dr*dr + di*di;
      srB = dr/dn; siB = -di/dn;
    }
    float2 vB[4];
    {
      float2 t0 = make_float2(cb[0].x*srB - cb[0].y*siB, cb[0].x*siB + cb[0].y*srB);
      vB[0] = (lane > prB) ? t0 : ((lane == prB) ? make_float2(1.f, 0.f)
                                                 : make_float2(0.f, 0.f));
    }
    vB[1] = make_float2(cb[1].x*srB - cb[1].y*siB, cb[1].x*siB + cb[1].y*srB);
    vB[2] = make_float2(cb[2].x*srB - cb[2].y*siB, cb[2].x*siB + cb[2].y*srB);
    vB[3] = make_float2(cb[3].x*srB - cb[3].y*siB, cb[3].x*siB + cb[3].y*srB);
    {
      float2 o0 = (lane < prB) ? cb[0]
                : ((lane == prB) ? make_float2(btB, 0.f) : vB[0]);
      sfin[jlA+1][lane] = o0;
      if (1 < MCHW) sfin[jlA+1][64 + lane]  = vB[1];
      if (2 < MCHW) sfin[jlA+1][128 + lane] = vB[2];
      if (3 < MCHW) sfin[jlA+1][192 + lane] = vB[3];
    }
    // --- g = vB^H vA ---
    float gr = vB[0].x*vA[0].x + vB[0].y*vA[0].y;
    float gi = vB[0].x*vA[0].y - vB[0].y*vA[0].x;
    if (1 < MCHW) { gr += vB[1].x*vA[1].x + vB[1].y*vA[1].y;
                    gi += vB[1].x*vA[1].y - vB[1].y*vA[1].x; }
    if (2 < MCHW) { gr += vB[2].x*vA[2].x + vB[2].y*vA[2].y;
                    gi += vB[2].x*vA[2].y - vB[2].y*vA[2].x; }
    if (3 < MCHW) { gr += vB[3].x*vA[3].x + vB[3].y*vA[3].y;
                    gi += vB[3].x*vA[3].y - vB[3].y*vA[3].x; }
    gr = wredsum(gr); gi = wredsum(gi);
    // --- publish ---
    snA[buf][lane] = vA[0]; snA[buf][64+lane] = vA[1];
    snA[buf][128+lane] = vA[2]; snA[buf][192+lane] = vA[3];
    snB[buf][lane] = vB[0]; snB[buf][64+lane] = vB[1];
    snB[buf][128+lane] = vB[2]; snB[buf][192+lane] = vB[3];
    if (lane == 0) {
      sscalAB[buf] = make_float4(trA, tiA, trB, tiB);
      sg[buf] = make_float2(gr, gi);
      stauOut[jlA]   = make_float2(trA, tiA);
      stauOut[jlA+1] = make_float2(trB, tiB);
    }
  };

  // prologue: wave 0 derives pair (0,1) -> buffer 0
  if (w == 0) derive_pair(col[0], col[1], 0, 0);
  __syncthreads();

  #pragma unroll 1
  for (int m = 0; m < 15; ++m) {
    const int cur = m & 1, nxt = cur ^ 1;
    float2 vA0 = snA[cur][lane],       vA1 = snA[cur][64 + lane],
           vA2 = snA[cur][128 + lane], vA3 = snA[cur][192 + lane];
    float2 vB0 = snB[cur][lane],       vB1 = snB[cur][64 + lane],
           vB2 = snB[cur][128 + lane], vB3 = snB[cur][192 + lane];
    float4 sc = sscalAB[cur];
    float2 g  = sg[cur];
    #pragma unroll
    for (int lc = 0; lc < 2; ++lc) {
      int cl = 2*w + lc;
      if (cl > 2*m + 1) {
        float d1r, d1i, d2r, d2i;
        { float2 a = col[lc][0];
          d1r = vA0.x*a.x + vA0.y*a.y; d1i = vA0.x*a.y - vA0.y*a.x;
          d2r = vB0.x*a.x + vB0.y*a.y; d2i = vB0.x*a.y - vB0.y*a.x; }
        if (1 < MCHW) { float2 a = col[lc][1];
          d1r += vA1.x*a.x + vA1.y*a.y; d1i += vA1.x*a.y - vA1.y*a.x;
          d2r += vB1.x*a.x + vB1.y*a.y; d2i += vB1.x*a.y - vB1.y*a.x; }
        if (2 < MCHW) { float2 a = col[lc][2];
          d1r += vA2.x*a.x + vA2.y*a.y; d1i += vA2.x*a.y - vA2.y*a.x;
          d2r += vB2.x*a.x + vB2.y*a.y; d2i += vB2.x*a.y - vB2.y*a.x; }
        if (3 < MCHW) { float2 a = col[lc][3];
          d1r += vA3.x*a.x + vA3.y*a.y; d1i += vA3.x*a.y - vA3.y*a.x;
          d2r += vB3.x*a.x + vB3.y*a.y; d2i += vB3.x*a.y - vB3.y*a.x; }
        d1r = wredsum(d1r); d1i = wredsum(d1i);
        d2r = wredsum(d2r); d2i = wredsum(d2i);
        float f1r = sc.x*d1r + sc.y*d1i;           // conj(tauA)*d1
        float f1i = sc.x*d1i - sc.y*d1r;
        float d2cr = d2r - (f1r*g.x - f1i*g.y);    // d2 - f1*g
        float d2ci = d2i - (f1r*g.y + f1i*g.x);
        float f2r = sc.z*d2cr + sc.w*d2ci;         // conj(tauB)*d2'
        float f2i = sc.z*d2ci - sc.w*d2cr;
        { col[lc][0].x -= f1r*vA0.x - f1i*vA0.y + f2r*vB0.x - f2i*vB0.y;
          col[lc][0].y -= f1r*vA0.y + f1i*vA0.x + f2r*vB0.y + f2i*vB0.x; }
        if (1 < MCHW) {
          col[lc][1].x -= f1r*vA1.x - f1i*vA1.y + f2r*vB1.x - f2i*vB1.y;
          col[lc][1].y -= f1r*vA1.y + f1i*vA1.x + f2r*vB1.y + f2i*vB1.x; }
        if (2 < MCHW) {
          col[lc][2].x -= f1r*vA2.x - f1i*vA2.y + f2r*vB2.x - f2i*vB2.y;
          col[lc][2].y -= f1r*vA2.y + f1i*vA2.x + f2r*vB2.y + f2i*vB2.x; }
        if (3 < MCHW) {
          col[lc][3].x -= f1r*vA3.x - f1i*vA3.y + f2r*vB3.x - f2i*vB3.y;
          col[lc][3].y -= f1r*vA3.y + f1i*vA3.x + f2r*vB3.y + f2i*vB3.x; }
      }
    }
    if (w == m + 1) derive_pair(col[0], col[1], 2*m + 2, nxt);
    __syncthreads();
  }

  // ---- batch-write panel columns + taus to global ----
  #pragma unroll
  for (int it = 0; it < 8; ++it) {
    int idx = it*1024 + tid;
    int c = idx >> 8, rr = idx & 255;
    if (rr < RW) A[(size_t)(32*P + c)*D_ + J0W + rr] = sfin[c][rr];
  }
  if (tid < 32) tau[32*P + tid] = stauOut[tid];
}

// ---------------------------------------------------------------------------
// zung2r, PAIRED (r16): per iteration apply H_i, H_{i-1} together.
// ---------------------------------------------------------------------------
__global__ __launch_bounds__(256, 1) void qr_bwd_kernel(
    const float2* __restrict__ A, const float2* __restrict__ tau,
    u16* __restrict__ Benc, u16* __restrict__ Bdec)
{
  const int lane = threadIdx.x & 63;
  const int w = threadIdx.x >> 6;
  const int c = blockIdx.x * 4 + w;          // column 0..255
  __shared__ float2 stau[256];
  if (threadIdx.x < 256) stau[threadIdx.x] = tau[threadIdx.x];
  __syncthreads();

  float2 q[4];
  #pragma unroll
  for (int m = 0; m < 4; ++m) {
    q[m] = make_float2(0.f, 0.f);
    if (m*64 + lane == c) q[m].x = 1.f;      // q = e_c
  }
  float2 A0[4], A1[4], A2[4], A3[4];
  {
    int i0 = c, i1 = (c >= 1) ? c-1 : 0, i2 = (c >= 2) ? c-2 : 0,
        i3 = (c >= 3) ? c-3 : 0;
    #pragma unroll
    for (int m = 0; m < 4; ++m) {
      A0[m] = A[(size_t)i0*D_ + m*64 + lane];
      A1[m] = A[(size_t)i1*D_ + m*64 + lane];
      A2[m] = A[(size_t)i2*D_ + m*64 + lane];
      A3[m] = A[(size_t)i3*D_ + m*64 + lane];
    }
  }

  int i = c;
  #pragma unroll 1
  while (i >= 1) {                           // pair (i, i-1)
    float2 ta = stau[i], tb = stau[i-1];
    float2 vI[4], vJ[4];
    #pragma unroll
    for (int m = 0; m < 4; ++m) {
      int r = m*64 + lane;
      vI[m] = (r > i)   ? A0[m] : ((r == i)   ? make_float2(1.f, 0.f)
                                              : make_float2(0.f, 0.f));
      vJ[m] = (r > i-1) ? A1[m] : ((r == i-1) ? make_float2(1.f, 0.f)
                                              : make_float2(0.f, 0.f));
    }
    float2 P0[4], P1[4];
    {
      int n0 = (i >= 4) ? i-4 : 0, n1 = (i >= 5) ? i-5 : 0;
      #pragma unroll
      for (int m = 0; m < 4; ++m) {
        P0[m] = A[(size_t)n0*D_ + m*64 + lane];
        P1[m] = A[(size_t)n1*D_ + m*64 + lane];
      }
    }
    float d1r = 0.f, d1i = 0.f, d2r = 0.f, d2i = 0.f, gr = 0.f, gi = 0.f;
    #pragma unroll
    for (int m = 0; m < 4; ++m) {
      d1r += vI[m].x*q[m].x + vI[m].y*q[m].y;    // conj(vI)*q
      d1i += vI[m].x*q[m].y - vI[m].y*q[m].x;
      d2r += vJ[m].x*q[m].x + vJ[m].y*q[m].y;    // conj(vJ)*q
      d2i += vJ[m].x*q[m].y - vJ[m].y*q[m].x;
      gr  += vJ[m].x*vI[m].x + vJ[m].y*vI[m].y;  // conj(vJ)*vI
      gi  += vJ[m].x*vI[m].y - vJ[m].y*vI[m].x;
    }
    d1r = wredsum(d1r); d1i = wredsum(d1i);
    d2r = wredsum(d2r); d2i = wredsum(d2i);
    gr  = wredsum(gr);  gi  = wredsum(gi);
    float f1r = ta.x*d1r - ta.y*d1i;             // f1 = tauI*d1 (non-conj)
    float f1i = ta.x*d1i + ta.y*d1r;
    float d2cr = d2r - (f1r*gr - f1i*gi);        // d2 - f1*g
    float d2ci = d2i - (f1r*gi + f1i*gr);
    float f2r = tb.x*d2cr - tb.y*d2ci;           // f2 = tauJ*d2'
    float f2i = tb.x*d2ci + tb.y*d2cr;
    #pragma unroll
    for (int m = 0; m < 4; ++m) {
      q[m].x -= f1r*vI[m].x - f1i*vI[m].y + f2r*vJ[m].x - f2i*vJ[m].y;
      q[m].y -= f1r*vI[m].y + f1i*vI[m].x + f2r*vJ[m].y + f2i*vJ[m].x;
      A0[m] = A2[m]; A1[m] = A3[m]; A2[m] = P0[m]; A3[m] = P1[m];
    }
    i -= 2;
  }
  if (i == 0) {                                 // leftover reflector 0
    float2 tt = stau[0];
    float2 v0[4];
    #pragma unroll
    for (int m = 0; m < 4; ++m) {
      int r = m*64 + lane;
      v0[m] = (r > 0) ? A0[m] : make_float2(1.f, 0.f);   // r==0 -> 1
    }
    float wr = 0.f, wi = 0.f;
    #pragma unroll
    for (int m = 0; m < 4; ++m) {
      wr += v0[m].x*q[m].x + v0[m].y*q[m].y;
      wi += v0[m].x*q[m].y - v0[m].y*q[m].x;
    }
    wr = wredsum(wr); wi = wredsum(wi);
    float fr = tt.x*wr - tt.y*wi;
    float fi = tt.x*wi + tt.y*wr;
    #pragma unroll
    for (int m = 0; m < 4; ++m) {
      q[m].x -= fr*v0[m].x - fi*v0[m].y;
      q[m].y -= fr*v0[m].y + fi*v0[m].x;
    }
  }

  #pragma unroll
  for (int m = 0; m < 4; ++m) {
    int r = m*64 + lane;
    u16 qre = f2bf(q[m].x), qim = f2bf(q[m].y), qimn = f2bf(-q[m].y);
    Benc[(size_t)c*D_ + r]              = qre;
    Benc[(size_t)(c+256)*D_ + r]        = qim;
    Bdec[(size_t)c*512 + r]             = qre;
    Bdec[(size_t)c*512 + 256 + r]       = qimn;
    Bdec[(size_t)(c+256)*512 + r]       = qim;
    Bdec[(size_t)(c+256)*512 + 256 + r] = qre;
  }
}

// ---------------------------------------------------------------------------
// Per-(b,t,d) coefficient tables (L2-resident; keeps scan memory-bound).
// ---------------------------------------------------------------------------
__global__ __launch_bounds__(256) void coef_kernel(
  const float* __restrict__ dt, const float* __restrict__ lam_re, const float* __restrict__ lam_im,
  const float* __restrict__ noise_raw,
  float* __restrict__ c_dre, float* __restrict__ c_dim, float* __restrict__ c_fre,
  float* __restrict__ c_fim, float* __restrict__ c_ns)
{
  int bt = blockIdx.x; int d = threadIdx.x;
  float dtv = dt[bt];
  float lr = lam_re[d], li = lam_im[d];
  float lam_r = fmaxf(-log1pf(expf(-lr)), -0.3f);     // -softplus(-x), clamp
  float ar = dtv*lam_r, ai = dtv*li;
  float er = expf(ar);
  float dre = er*cosf(ai), dim_ = er*sinf(ai);
  float t = lam_r + 1e-12f;
  float sgn = (t > 0.f) ? 1.f : ((t < 0.f) ? -1.f : 0.f);
  float den_re = lam_r + 1e-8f*sgn, den_im = li;      // lam_safe
  float nr = dre - 1.f, ni = dim_;
  float d2 = den_re*den_re + den_im*den_im;
  float fre = (nr*den_re + ni*den_im)/d2;
  float fim = (ni*den_re - nr*den_im)/d2;
  float ns = sqrtf(fmaxf(dtv,0.f)) * log1pf(expf(noise_raw[d])) * 0.01f;
  int idx = bt*D_+d;
  c_dre[idx]=dre; c_dim[idx]=dim_; c_fre[idx]=fre; c_fim[idx]=fim; c_ns[idx]=ns;
}

// ---------------------------------------------------------------------------
// bf16 MFMA GEMM, 128x128 tile, 4 waves, BK=64, 16x16x32 MFMA.
// 1D grid 2048 with L2-locality swizzle: bid = (mg*4 + n)*8 + ml — the 4
// N-tiles of one M-tile are 8 ids apart (same XCD under %8 round-robin) and
// temporally adjacent, so the A-tile is fetched once per XCD (r16: FETCH
// 133 MB vs 64.5 ideal because N-tiles ran ~512 slots apart).
// ---------------------------------------------------------------------------
#define LDT 72

__device__ __forceinline__ void gemm_tile_idx(int bid, int& m0, int& n0) {
  int ml = bid & 7, t = bid >> 3;
  int n = t & 3, mg = t >> 2;
  m0 = (mg*8 + ml)*128;
  n0 = n*128;
}

__global__ __launch_bounds__(256) void encode_gemm(
    const float* __restrict__ x, const u16* __restrict__ Bt,
    u16* __restrict__ xer16, u16* __restrict__ xei16)
{
  __shared__ u16 sA[128*LDT];
  __shared__ u16 sB[128*LDT];
  const int tid = threadIdx.x;
  const int lane = tid & 63, w = tid >> 6;
  const int wr = w >> 1, wc = w & 1;
  const int l15 = lane & 15, l4 = lane >> 4;
  int m0, n0;
  gemm_tile_idx(blockIdx.x, m0, n0);
  f32x4 acc[4][4] = {};
  for (int kb = 0; kb < 4; ++kb) {
    #pragma unroll
    for (int i = 0; i < 4; ++i) {
      int chunk = i*256 + tid;
      int row = chunk >> 3, k0 = (chunk & 7) * 8;
      const float* xs = x + (size_t)(m0+row)*D_ + kb*64 + k0;
      float4 f0 = *(const float4*)xs;
      float4 f1 = *(const float4*)(xs + 4);
      int4 va;
      va.x = (int)((unsigned)f2bf(f0.x) | ((unsigned)f2bf(f0.y) << 16));
      va.y = (int)((unsigned)f2bf(f0.z) | ((unsigned)f2bf(f0.w) << 16));
      va.z = (int)((unsigned)f2bf(f1.x) | ((unsigned)f2bf(f1.y) << 16));
      va.w = (int)((unsigned)f2bf(f1.z) | ((unsigned)f2bf(f1.w) << 16));
      int4 vb = *(const int4*)(Bt + (size_t)(n0+row)*D_ + kb*64 + k0);
      *(int4*)&sA[row*LDT + k0] = va;
      *(int4*)&sB[row*LDT + k0] = vb;
    }
    __syncthreads();
    #pragma unroll
    for (int ks = 0; ks < 2; ++ks) {
      bf16x8 af[4], bb[4];
      #pragma unroll
      for (int mf = 0; mf < 4; ++mf)
        af[mf] = *(const bf16x8*)&sA[(wr*64 + mf*16 + l15)*LDT + ks*32 + l4*8];
      #pragma unroll
      for (int nf = 0; nf < 4; ++nf)
        bb[nf] = *(const bf16x8*)&sB[(wc*64 + nf*16 + l15)*LDT + ks*32 + l4*8];
      #pragma unroll
      for (int mf = 0; mf < 4; ++mf)
        #pragma unroll
        for (int nf = 0; nf < 4; ++nf)
          acc[mf][nf] = __builtin_amdgcn_mfma_f32_16x16x32_bf16(
              af[mf], bb[nf], acc[mf][nf], 0, 0, 0);
    }
    __syncthreads();
  }
  #pragma unroll
  for (int mf = 0; mf < 4; ++mf)
    #pragma unroll
    for (int nf = 0; nf < 4; ++nf)
      #pragma unroll
      for (int r = 0; r < 4; ++r) {
        int row = m0 + wr*64 + mf*16 + l4*4 + r;
        int col = n0 + wc*64 + nf*16 + l15;
        float v = acc[mf][nf][r];
        if (col < 256) xer16[(size_t)row*D_ + col] = f2bf(v);
        else           xei16[(size_t)row*D_ + col - 256] = f2bf(-v);
      }
}

__global__ __launch_bounds__(256) void decode_gemm(
    const u16* __restrict__ hre16, const u16* __restrict__ him16,
    const u16* __restrict__ Bt, float* __restrict__ out)
{
  __shared__ u16 sA[128*LDT];
  __shared__ u16 sB[128*LDT];
  const int tid = threadIdx.x;
  const int lane = tid & 63, w = tid >> 6;
  const int wr = w >> 1, wc = w & 1;
  const int l15 = lane & 15, l4 = lane >> 4;
  int m0, n0;
  gemm_tile_idx(blockIdx.x, m0, n0);
  f32x4 acc[4][4] = {};
  for (int kb = 0; kb < 8; ++kb) {
    const u16* aplane = (kb < 4) ? hre16 : him16;
    const int kk = (kb & 3) * 64;
    #pragma unroll
    for (int i = 0; i < 4; ++i) {
      int chunk = i*256 + tid;
      int row = chunk >> 3, k0 = (chunk & 7) * 8;
      int4 va = *(const int4*)(aplane + (size_t)(m0+row)*D_ + kk + k0);
      int4 vb = *(const int4*)(Bt + (size_t)(n0+row)*512 + kb*64 + k0);
      *(int4*)&sA[row*LDT + k0] = va;
      *(int4*)&sB[row*LDT + k0] = vb;
    }
    __syncthreads();
    #pragma unroll
    for (int ks = 0; ks < 2; ++ks) {
      bf16x8 af[4], bb[4];
      #pragma unroll
      for (int mf = 0; mf < 4; ++mf)
        af[mf] = *(const bf16x8*)&sA[(wr*64 + mf*16 + l15)*LDT + ks*32 + l4*8];
      #pragma unroll
      for (int nf = 0; nf < 4; ++nf)
        bb[nf] = *(const bf16x8*)&sB[(wc*64 + nf*16 + l15)*LDT + ks*32 + l4*8];
      #pragma unroll
      for (int mf = 0; mf < 4; ++mf)
        #pragma unroll
        for (int nf = 0; nf < 4; ++nf)
          acc[mf][nf] = __builtin_amdgcn_mfma_f32_16x16x32_bf16(
              af[mf], bb[nf], acc[mf][nf], 0, 0, 0);
    }
    __syncthreads();
  }
  #pragma unroll
  for (int mf = 0; mf < 4; ++mf)
    #pragma unroll
    for (int nf = 0; nf < 4; ++nf)
      #pragma unroll
      for (int r = 0; r < 4; ++r) {
        int row = m0 + wr*64 + mf*16 + l4*4 + r;
        int col = n0 + wc*64 + nf*16 + l15;
        float v = acc[mf][nf][r];
        if (col < 256) out[(size_t)row*D_ + col] = v;
        else           out[PLANE + (size_t)row*D_ + col - 256] = v;
      }
}

// ---------------------------------------------------------------------------
// Scan: reads bf16 x_enc planes + fp32 eps + coef tables (L2-resident);
// writes bf16 h planes. One block per (b,n); thread = d. Memory-bound.
// ---------------------------------------------------------------------------
__global__ __launch_bounds__(256) void scan_kernel(
  const float* __restrict__ eps,
  const float* __restrict__ c_dre, const float* __restrict__ c_dim,
  const float* __restrict__ c_fre, const float* __restrict__ c_fim, const float* __restrict__ c_ns,
  const u16* __restrict__ xer16, const u16* __restrict__ xei16,
  u16* __restrict__ hre16, u16* __restrict__ him16)
{
  int bx = blockIdx.x;
  int b = bx >> 9, n = bx & 511;
  int d = threadIdx.x;
  float hr = 0.f, hi = 0.f;
  for (int t = 0; t < T_; ++t) {
    int bt = b*T_ + t;
    int cidx = bt*D_ + d;
    float dre = c_dre[cidx], dim_ = c_dim[cidx];
    float fre = c_fre[cidx], fim = c_fim[cidx];
    float ns  = c_ns[cidx];
    size_t idx = ((size_t)bt*N_ + n)*D_ + d;
    float xr = bf2f(xer16[idx]), xi = bf2f(xei16[idx]), ep = eps[idx];
    float br = fre*xr - fim*xi + ep*ns;
    float bi = fre*xi + fim*xr;
    float nr2 = dre*hr - dim_*hi + br;
    float ni2 = dre*hi + dim_*hr + bi;
    hr = nr2; hi = ni2;
    hre16[idx] = f2bf(hr); him16[idx] = f2bf(hi);
  }
}

// ---------------------------------------------------------------------------
extern "C" void kernel_launch(void* const* d_in, const int* in_sizes, int n_in,
                              void* d_out, int out_size, void* d_ws, size_t ws_size,
                              hipStream_t stream)
{
  const float* x         = (const float*)d_in[0];
  const float* dt        = (const float*)d_in[1];
  const float* eps       = (const float*)d_in[2];
  const float* ure_raw   = (const float*)d_in[3];
  const float* uim_raw   = (const float*)d_in[4];
  const float* lam_re    = (const float*)d_in[5];
  const float* lam_im    = (const float*)d_in[6];
  const float* noise_raw = (const float*)d_in[7];
  float* out = (float*)d_out;

  // ws layout (132 MB total):
  //   0       A float2[65536]            512 KB
  //   512K    tau float2[256]            2 KB
  //   1M      Benc bf16 [512][256]       256 KB
  //   1.5M    Bdec bf16 [512][512]       512 KB
  //   2M      coef tables 5 x 128 KB     640 KB
  //   4M      hre16 bf16 [M][256] 32 MB
  //   36M     xer16 32 MB
  //   68M     xei16 32 MB
  //   100M    him16 32 MB
  char* ws = (char*)d_ws;
  float2* A    = (float2*)(ws);
  float2* tau  = (float2*)(ws + 524288);
  u16* Benc    = (u16*)(ws + (1<<20));
  u16* Bdec    = (u16*)(ws + 1572864);
  float* c_dre = (float*)(ws + (2<<20));
  float* c_dim = c_dre + B_*T_*D_;
  float* c_fre = c_dim + B_*T_*D_;
  float* c_fim = c_fre + B_*T_*D_;
  float* c_ns  = c_fim + B_*T_*D_;
  u16* hre16   = (u16*)(ws + ((size_t)4<<20));
  u16* xer16   = (u16*)(ws + ((size_t)36<<20));
  u16* xei16   = (u16*)(ws + ((size_t)68<<20));
  u16* him16   = (u16*)(ws + ((size_t)100<<20));

  qr_megastep<0><<<8, 1024, 0, stream>>>(ure_raw, uim_raw, A, tau);
  qr_megastep<1><<<7, 1024, 0, stream>>>(ure_raw, uim_raw, A, tau);
  qr_megastep<2><<<6, 1024, 0, stream>>>(ure_raw, uim_raw, A, tau);
  qr_megastep<3><<<5, 1024, 0, stream>>>(ure_raw, uim_raw, A, tau);
  qr_megastep<4><<<4, 1024, 0, stream>>>(ure_raw, uim_raw, A, tau);
  qr_megastep<5><<<3, 1024, 0, stream>>>(ure_raw, uim_raw, A, tau);
  qr_megastep<6><<<2, 1024, 0, stream>>>(ure_raw, uim_raw, A, tau);
  qr_megastep<7><<<1, 1024, 0, stream>>>(ure_raw, uim_raw, A, tau);
  qr_bwd_kernel<<<64, 256, 0, stream>>>(A, tau, Benc, Bdec);
  coef_kernel<<<B_*T_, 256, 0, stream>>>(dt, lam_re, lam_im, noise_raw,
                                         c_dre, c_dim, c_fre, c_fim, c_ns);
  encode_gemm<<<2048, 256, 0, stream>>>(x, Benc, xer16, xei16);
  scan_kernel<<<B_*N_, 256, 0, stream>>>(eps, c_dre, c_dim, c_fre, c_fim, c_ns,
                                         xer16, xei16, hre16, him16);
  decode_gemm<<<2048, 256, 0, stream>>>(hre16, him16, Bdec, out);
}